// Round 7
// baseline (17677.905 us; speedup 1.0000x reference)
//
#include <hip/hip_runtime.h>
#include <math.h>

// ---------------------------------------------------------------------------
// SpatialAttentionModel on MI355X.
// R7: k_lstm split 4-ways. R4-R6 proved the 512KB Whh cannot be made
// VGPR-resident (allocator spills to L2-scratch; identical 4500cyc/step
// L2-stream bound). New structure: 256 blocks = 64 chains x 4 gate-quarters;
// each block's 256x256 weight slice (128KB f16) lives ENTIRELY in LDS.
// Per step: block computes its 256 activated gates, publishes 1KB via
// agent-scope atomics (double-buffered), spins on 3 partner flags, then all
// 4 blocks redundantly update c,h. 1 block/CU x 256 CUs -> co-resident.
// ---------------------------------------------------------------------------

typedef _Float16 h2_t __attribute__((ext_vector_type(2)));

#if __has_builtin(__builtin_amdgcn_fdot2)
#define HAVE_FDOT2 1
#else
#define HAVE_FDOT2 0
#endif

__device__ __forceinline__ float dot2(unsigned w, unsigned h, float acc) {
#if HAVE_FDOT2
  return __builtin_amdgcn_fdot2(__builtin_bit_cast(h2_t, w),
                                __builtin_bit_cast(h2_t, h), acc, false);
#else
  h2_t a = __builtin_bit_cast(h2_t, w);
  h2_t b = __builtin_bit_cast(h2_t, h);
  return acc + (float)a[0] * (float)b[0] + (float)a[1] * (float)b[1];
#endif
}

__device__ __forceinline__ unsigned pack2(float a, float b) {
  h2_t p;
  p[0] = (_Float16)a;
  p[1] = (_Float16)b;
  return __builtin_bit_cast(unsigned, p);
}

__device__ __forceinline__ float sigmoid_f(float x) {
  return __builtin_amdgcn_rcpf(1.f + __expf(-x));
}
__device__ __forceinline__ float tanh_f(float x) {
  return 1.f - 2.f * __builtin_amdgcn_rcpf(1.f + __expf(2.f * x));
}

#define AST_RLX(p, v) \
  __hip_atomic_store((p), (v), __ATOMIC_RELAXED, __HIP_MEMORY_SCOPE_AGENT)
#define ALD_RLX(p) \
  __hip_atomic_load((p), __ATOMIC_RELAXED, __HIP_MEMORY_SCOPE_AGENT)

// ---------------------------------------------------------------------------
// Pack Whh for k_lstm4: w4[q][seg][p], q<4 gate quarter, seg = r*2+half
// (r<256 local row, half<2 k-half), p<64: packed f16 pair of
// Whh[256q + r][2*(64*half + p) .. +1].
__global__ void k_pack_w4(const float* __restrict__ Whh,
                          unsigned* __restrict__ w4) {
  const int idx = blockIdx.x * 256 + threadIdx.x;  // < 131072
  const int p = idx & 63;
  const int seg = (idx >> 6) & 511;
  const int q = idx >> 15;
  const int r = seg >> 1, half = seg & 1;
  const int row = q * 256 + r;
  const int P = half * 64 + p;
  w4[idx] = pack2(Whh[row * 256 + 2 * P], Whh[row * 256 + 2 * P + 1]);
}

// Zero the sync flags (re-run every call: poison/replay safe).
__global__ void k_zero(int* __restrict__ flags) {
  flags[threadIdx.x] = 0;
}

// Generic f32 -> packed-f16-pair converter (contiguous rows, even cols).
__global__ void k_packh2(const float* __restrict__ src,
                         unsigned* __restrict__ dst, int n) {
  const int i = blockIdx.x * 256 + threadIdx.x;
  if (i < n) dst[i] = pack2(src[2 * i], src[2 * i + 1]);
}

// xg[t][b][j] = gaze[b,t,:]·Wih[j,:] + bih[j] + bhh[j],  t in [0,31)
__global__ void k_xg(const float* __restrict__ gaze,
                     const float* __restrict__ Wih,
                     const float* __restrict__ bih,
                     const float* __restrict__ bhh,
                     float* __restrict__ xg) {
  const int idx = blockIdx.x * 256 + threadIdx.x;
  if (idx >= 31 * 64 * 1024) return;
  const int j = idx & 1023;
  const int b = (idx >> 10) & 63;
  const int t = idx >> 16;
  const float* gz = gaze + (b * 32 + t) * 3;
  xg[idx] = gz[0] * Wih[j * 3 + 0] + gz[1] * Wih[j * 3 + 1] +
            gz[2] * Wih[j * 3 + 2] + bih[j] + bhh[j];
}

// h0/c0: h = tanh(tanh( tanh(mg@Wh1.T+bh1) @ Wh2.T + bh2 )), same for c.
__global__ void k_init(const float* __restrict__ gaze,
                       const float* __restrict__ Wh1, const float* __restrict__ bh1,
                       const float* __restrict__ Wh2, const float* __restrict__ bh2,
                       const float* __restrict__ Wc1, const float* __restrict__ bc1,
                       const float* __restrict__ Wc2, const float* __restrict__ bc2,
                       float* __restrict__ HH, float* __restrict__ c0) {
  const int b = blockIdx.x;
  const int tid = threadIdx.x;  // 256
  __shared__ float mg[3];
  __shared__ float t1h[256], t1c[256];
  if (tid < 3) {
    float s = 0.f;
    for (int t = 0; t < 32; t++) s += gaze[(b * 32 + t) * 3 + tid];
    mg[tid] = s * (1.f / 32.f);
  }
  __syncthreads();
  {
    float a = mg[0] * Wh1[tid * 3 + 0] + mg[1] * Wh1[tid * 3 + 1] +
              mg[2] * Wh1[tid * 3 + 2] + bh1[tid];
    t1h[tid] = tanhf(a);
    float c = mg[0] * Wc1[tid * 3 + 0] + mg[1] * Wc1[tid * 3 + 1] +
              mg[2] * Wc1[tid * 3 + 2] + bc1[tid];
    t1c[tid] = tanhf(c);
  }
  __syncthreads();
  float s1 = bh2[tid], s2 = bc2[tid];
  for (int k = 0; k < 256; k++) {
    s1 += t1h[k] * Wh2[tid * 256 + k];
    s2 += t1c[k] * Wc2[tid * 256 + k];
  }
  HH[b * 256 + tid] = tanhf(tanhf(s1));  // HH[0][b][k]
  c0[b * 256 + tid] = tanhf(tanhf(s2));
}

// ---------------------------------------------------------------------------
// The sequential LSTM chain, 4 blocks per batch chain.
// blockIdx: q = bid>>6 (gate quarter: 0=i,1=f,2=g,3=o), b = bid&63
// (partner blocks {b,64+b,128+b,192+b} are congruent mod 8 -> same XCD
// under round-robin dispatch; correctness does not depend on it).
// 512 threads: wave w, lane l; half = l>>5, r = w*32 + (l&31).
// Thread (r,half) reduces pairs [64*half, 64*half+64) of local row r from
// LDS-resident weights (stride-66 segments, 2-way banking = free), combines
// with its half-partner via shfl_xor(32).
// Cross-block exchange: double-buffered gbuf[2][64][4][256] f32 acts via
// relaxed agent atomics; flags[b][q] = monotonic step counter
// (release/acquire, agent scope).
__global__ __launch_bounds__(512) void k_lstm4(
    const float* __restrict__ xg, const unsigned* __restrict__ w4,
    const float* __restrict__ c0, float* __restrict__ HH,
    float* __restrict__ gbuf, int* __restrict__ flags) {
  const int bid = blockIdx.x;
  const int q = bid >> 6, b = bid & 63;
  const int tid = threadIdx.x;
  __shared__ __align__(16) unsigned wlds[512 * 66];  // 135168 B
  __shared__ __align__(16) unsigned h2l[128];

  // Stage this quarter's 256x256 f16 weight slice into LDS (one time).
  const unsigned* wsrc = w4 + q * 32768;
  for (int i = tid; i < 32768; i += 512)
    wlds[(i >> 6) * 66 + (i & 63)] = wsrc[i];

  const int w = tid >> 6, l = tid & 63;
  const int half = l >> 5;
  const int r = w * 32 + (l & 31);
  const unsigned* wbase = &wlds[(r * 2 + half) * 66];
  const unsigned* hbase = &h2l[half * 64];
  const bool isg = (q == 2);
  int* flg = flags + b * 4;

  float cst = (half == 0) ? c0[b * 256 + r] : 0.f;
  if (tid < 256) ((_Float16*)h2l)[tid] = (_Float16)HH[b * 256 + tid];
  __syncthreads();

  int s = 0;
  float hval = 0.f;
  for (int frame = 0; frame < 32; frame++) {
    const int L = frame ? frame : 1;
    for (int t = 0; t < L; t++) {
      s++;
      // ---- matvec over LDS weights + LDS h broadcast ----
      float a0 = 0.f, a1 = 0.f;
#pragma unroll
      for (int i2 = 0; i2 < 16; i2++) {
        const uint4 wq = *(const uint4*)&wbase[4 * i2];
        const uint4 hq = *(const uint4*)&hbase[4 * i2];
        if (i2 & 1) {
          a1 = dot2(wq.x, hq.x, a1);
          a1 = dot2(wq.y, hq.y, a1);
          a1 = dot2(wq.z, hq.z, a1);
          a1 = dot2(wq.w, hq.w, a1);
        } else {
          a0 = dot2(wq.x, hq.x, a0);
          a0 = dot2(wq.y, hq.y, a0);
          a0 = dot2(wq.z, hq.z, a0);
          a0 = dot2(wq.w, hq.w, a0);
        }
      }
      float tot = a0 + a1;
      tot += __shfl_xor(tot, 32);  // combine the two k-halves
      // ---- publish activated gate values ----
      float* gslot = gbuf + (((size_t)(s & 1) * 64 + b) * 4 + q) * 256;
      if (half == 0) {
        const float gv = tot + xg[(t * 64 + b) * 1024 + q * 256 + r];
        const float act = isg ? tanh_f(gv) : sigmoid_f(gv);
        AST_RLX(&gslot[r], act);
      }
      __threadfence();   // order act stores before flag (belt+braces)
      __syncthreads();   // all waves' stores drained (vmcnt0 before barrier)
      if (tid == 0)
        __hip_atomic_store(flg + q, s, __ATOMIC_RELEASE,
                           __HIP_MEMORY_SCOPE_AGENT);
      if (tid < 4) {
        while (__hip_atomic_load(flg + tid, __ATOMIC_ACQUIRE,
                                 __HIP_MEMORY_SCOPE_AGENT) < s) {
        }
      }
      __syncthreads();
      // ---- redundant c,h update in every block ----
      if (half == 0) {
        const float* sb = gbuf + (((size_t)(s & 1) * 64 + b) * 4) * 256;
        const float i_ = ALD_RLX(sb + r);
        const float f_ = ALD_RLX(sb + 256 + r);
        const float g_ = ALD_RLX(sb + 512 + r);
        const float o_ = ALD_RLX(sb + 768 + r);
        cst = f_ * cst + i_ * g_;
        hval = o_ * tanh_f(cst);
        ((_Float16*)h2l)[r] = (_Float16)hval;
      }
      __syncthreads();  // h2l ready for next step
    }
    if (q == 0 && half == 0) HH[((frame + 1) * 64 + b) * 256 + r] = hval;
  }
}

// Hl[i][b][p] = HH[i][b]·W_lh[p] + b_lh[p]. One block per frame.
__global__ void k_hl(const float* __restrict__ HH,
                     const unsigned* __restrict__ wlh_h2,
                     const float* __restrict__ blh, float* __restrict__ Hl) {
  const int i = blockIdx.x;
  const int tid = threadIdx.x;  // 256
  __shared__ __align__(16) unsigned Ah[64 * 132];
  __shared__ __align__(16) unsigned Bh[128 * 132];
  for (int idx = tid; idx < 64 * 128; idx += 256) {
    const int r = idx >> 7, kp = idx & 127;
    const float* s = HH + ((size_t)(i * 64 + r)) * 256 + 2 * kp;
    Ah[r * 132 + kp] = pack2(s[0], s[1]);
  }
  for (int idx = tid; idx < 128 * 128; idx += 256) {
    const int o = idx >> 7, kp = idx & 127;
    Bh[o * 132 + kp] = wlh_h2[o * 128 + kp];
  }
  __syncthreads();
  const int ry = tid >> 4, px = tid & 15;
  float acc[4][8];
#pragma unroll
  for (int k = 0; k < 4; k++)
#pragma unroll
    for (int j = 0; j < 8; j++) acc[k][j] = 0.f;
  for (int kb = 0; kb < 32; kb++) {
    uint4 a4[4], b4[8];
#pragma unroll
    for (int k = 0; k < 4; k++) a4[k] = *(const uint4*)&Ah[(16 * k + ry) * 132 + 4 * kb];
#pragma unroll
    for (int j = 0; j < 8; j++) b4[j] = *(const uint4*)&Bh[(16 * j + px) * 132 + 4 * kb];
#pragma unroll
    for (int k = 0; k < 4; k++)
#pragma unroll
      for (int j = 0; j < 8; j++) {
        acc[k][j] = dot2(a4[k].x, b4[j].x, acc[k][j]);
        acc[k][j] = dot2(a4[k].y, b4[j].y, acc[k][j]);
        acc[k][j] = dot2(a4[k].z, b4[j].z, acc[k][j]);
        acc[k][j] = dot2(a4[k].w, b4[j].w, acc[k][j]);
      }
  }
#pragma unroll
  for (int k = 0; k < 4; k++)
#pragma unroll
    for (int j = 0; j < 8; j++)
      Hl[(i * 64 + 16 * k + ry) * 128 + 16 * j + px] = acc[k][j] + blh[16 * j + px];
}

// Fused Vp GEMM + z. Rows = flattened (b,g) within frame i (2304 rows, tiles
// of 128). z[b,g] = sum_p w[p]*tanh(Hl[b,p] + Vp[b,g,p]).
__global__ void k_att_z(const float* __restrict__ cnn,
                        const unsigned* __restrict__ wcn_h2,
                        const float* __restrict__ bcn,
                        const float* __restrict__ Hl,
                        const float* __restrict__ wwt,
                        float* __restrict__ zbuf) {
  const int bid = blockIdx.x;  // 576 = 32 frames * 18 row tiles
  const int i = bid / 18, rt = bid - 18 * i;
  const int tid = threadIdx.x;  // 256
  const int r0 = rt * 128;
  __shared__ __align__(16) unsigned As[128 * 132];
  __shared__ __align__(16) unsigned Bs[128 * 132];
  __shared__ float zpart[128 * 16];
  __shared__ float Hls[5 * 128];
  __shared__ float wws[128];
  __shared__ float bcs[128];

  for (int idx = tid; idx < 128 * 128; idx += 256) {
    const int r = idx >> 7, kp = idx & 127;
    const int R = r0 + r;
    const int b = R / 36, g = R - b * 36;
    const float* src = cnn + (((size_t)b * 32 + i) * 36 + g) * 256 + 2 * kp;
    As[r * 132 + kp] = pack2(src[0], src[1]);
  }
  for (int idx = tid; idx < 128 * 128; idx += 256) {
    const int o = idx >> 7, kp = idx & 127;
    Bs[o * 132 + kp] = wcn_h2[o * 128 + kp];
  }
  const int bmin = r0 / 36;
  for (int idx = tid; idx < 5 * 128; idx += 256) {
    const int bb = bmin + (idx >> 7);
    if (bb < 64) Hls[idx] = Hl[(i * 64 + bb) * 128 + (idx & 127)];
  }
  if (tid < 128) {
    wws[tid] = wwt[tid];
    bcs[tid] = bcn[tid];
  }
  __syncthreads();

  const int ry = tid >> 4, px = tid & 15;
  float acc[8][8];
#pragma unroll
  for (int k = 0; k < 8; k++)
#pragma unroll
    for (int j = 0; j < 8; j++) acc[k][j] = bcs[16 * j + px];
  for (int kb = 0; kb < 32; kb++) {
    uint4 a4[8], b4[8];
#pragma unroll
    for (int k = 0; k < 8; k++) a4[k] = *(const uint4*)&As[(16 * k + ry) * 132 + 4 * kb];
#pragma unroll
    for (int j = 0; j < 8; j++) b4[j] = *(const uint4*)&Bs[(16 * j + px) * 132 + 4 * kb];
#pragma unroll
    for (int k = 0; k < 8; k++)
#pragma unroll
      for (int j = 0; j < 8; j++) {
        acc[k][j] = dot2(a4[k].x, b4[j].x, acc[k][j]);
        acc[k][j] = dot2(a4[k].y, b4[j].y, acc[k][j]);
        acc[k][j] = dot2(a4[k].z, b4[j].z, acc[k][j]);
        acc[k][j] = dot2(a4[k].w, b4[j].w, acc[k][j]);
      }
  }
#pragma unroll
  for (int k = 0; k < 8; k++) {
    const int r = 16 * k + ry;
    const int R = r0 + r;
    const int b = R / 36;
    const float* HlRow = &Hls[(b - bmin) * 128];
    float zp = 0.f;
#pragma unroll
    for (int j = 0; j < 8; j++) {
      const int po = 16 * j + px;
      zp += wws[po] * tanh_f(HlRow[po] + acc[k][j]);
    }
    zpart[r * 16 + px] = zp;
  }
  __syncthreads();
  if (tid < 128) {
    float z = 0.f;
#pragma unroll
    for (int x = 0; x < 16; x++) z += zpart[tid * 16 + x];
    const int R = r0 + tid;
    const int b = R / 36, g = R - b * 36;
    zbuf[(i * 64 + b) * 36 + g] = z;
  }
}

// Scrambled softmax + weighted V sum; builds fc = [spatial_feat | h_next].
__global__ void k_att_sf(const float* __restrict__ cnn,
                         const float* __restrict__ zbuf,
                         const float* __restrict__ HH,
                         float* __restrict__ fc) {
  const int bid = blockIdx.x;  // 2048 = i*64 + b
  const int i = bid >> 6, b = bid & 63;
  const int tid = threadIdx.x;  // 256
  __shared__ float zl[36];
  __shared__ float el[40];
  __shared__ float red[1];
  if (tid < 36) {
    const int idx = b * 36 + tid;  // scramble: z.T.reshape(64,36)
    zl[tid] = zbuf[(i * 64 + (idx & 63)) * 36 + (idx >> 6)];
  }
  __syncthreads();
  if (tid == 0) {
    float m = zl[0];
    for (int g = 1; g < 36; g++) m = fmaxf(m, zl[g]);
    float s = 0.f;
    for (int g = 0; g < 36; g++) {
      const float e = __expf(zl[g] - m);
      el[g] = e;
      s += e;
    }
    red[0] = 1.f / s;
  }
  __syncthreads();
  const float inv = red[0];
  float accv = 0.f;
  const float* Vb = cnn + (((size_t)b * 32 + i) * 36) * 256 + tid;
#pragma unroll 4
  for (int g = 0; g < 36; g++) accv += el[g] * Vb[g * 256];
  fc[(size_t)bid * 512 + tid] = accv * inv;
  fc[(size_t)bid * 512 + 256 + tid] = HH[((i + 1) * 64 + b) * 256 + tid];
}

// MLP layers 1/2: (2048,512)@(512,512)+b, output packed f16 pairs.
template <int SRCMODE>  // 0: f32 src (fc), 1: packed-h2 src
__global__ void k_mlp(const void* __restrict__ src,
                      const unsigned* __restrict__ wh2,
                      const float* __restrict__ bias,
                      unsigned* __restrict__ dst) {
  const int bid = blockIdx.x;  // 128 = 32 n-tiles * 4 o-tiles
  const int nb = bid >> 2, ob = bid & 3;
  const int n0 = nb * 64, o0 = ob * 128;
  const int tid = threadIdx.x;
  __shared__ __align__(16) unsigned As[64 * 132];
  __shared__ __align__(16) unsigned Bs[128 * 132];
  const int ry = tid >> 4, px = tid & 15;
  float acc[4][8];
#pragma unroll
  for (int k = 0; k < 4; k++)
#pragma unroll
    for (int m = 0; m < 8; m++)
      acc[k][m] = bias[o0 + 32 * (m >> 1) + 2 * px + (m & 1)];
  for (int kc = 0; kc < 2; kc++) {
    __syncthreads();
    for (int idx = tid; idx < 64 * 128; idx += 256) {
      const int r = idx >> 7, kp = idx & 127;
      if (SRCMODE == 0) {
        const float* s = (const float*)src + ((size_t)(n0 + r)) * 512 + kc * 256 + 2 * kp;
        As[r * 132 + kp] = pack2(s[0], s[1]);
      } else {
        As[r * 132 + kp] = ((const unsigned*)src)[((size_t)(n0 + r)) * 256 + kc * 128 + kp];
      }
    }
    for (int idx = tid; idx < 128 * 128; idx += 256) {
      const int o = idx >> 7, kp = idx & 127;
      Bs[o * 132 + kp] = wh2[((size_t)(o0 + o)) * 256 + kc * 128 + kp];
    }
    __syncthreads();
    for (int kb = 0; kb < 32; kb++) {
      uint4 a4[4], b4[8];
#pragma unroll
      for (int k = 0; k < 4; k++)
        a4[k] = *(const uint4*)&As[(16 * k + ry) * 132 + 4 * kb];
#pragma unroll
      for (int m = 0; m < 8; m++)
        b4[m] = *(const uint4*)&Bs[(32 * (m >> 1) + 2 * px + (m & 1)) * 132 + 4 * kb];
#pragma unroll
      for (int k = 0; k < 4; k++)
#pragma unroll
        for (int m = 0; m < 8; m++) {
          acc[k][m] = dot2(a4[k].x, b4[m].x, acc[k][m]);
          acc[k][m] = dot2(a4[k].y, b4[m].y, acc[k][m]);
          acc[k][m] = dot2(a4[k].z, b4[m].z, acc[k][m]);
          acc[k][m] = dot2(a4[k].w, b4[m].w, acc[k][m]);
        }
    }
  }
#pragma unroll
  for (int k = 0; k < 4; k++) {
    const int n = n0 + 16 * k + ry;
#pragma unroll
    for (int j = 0; j < 4; j++)
      dst[(size_t)n * 256 + (o0 >> 1) + 16 * j + px] =
          pack2(acc[k][2 * j], acc[k][2 * j + 1]);
  }
}

// Final layer: (2048,512) -> 6 classes.
__global__ void k_mlp3(const unsigned* __restrict__ y2h2,
                       const unsigned* __restrict__ wm3h2,
                       const float* __restrict__ bm3,
                       float* __restrict__ out) {
  const int nb = blockIdx.x;  // 32
  const int tid = threadIdx.x;
  __shared__ __align__(16) unsigned Ys[64 * 256];
  __shared__ __align__(16) unsigned Ws[6 * 256];
  for (int idx = tid; idx < 64 * 256; idx += 256)
    Ys[idx] = y2h2[(size_t)nb * 64 * 256 + idx];
  for (int idx = tid; idx < 6 * 256; idx += 256) Ws[idx] = wm3h2[idx];
  __syncthreads();
  for (int u = 0; u < 2; u++) {
    const int idx = tid + u * 256;
    if (idx < 384) {
      const int nl = idx / 6, c = idx - 6 * nl;
      float a0 = 0.f, a1 = 0.f;
#pragma unroll
      for (int kq = 0; kq < 64; kq++) {
        const uint4 y4 = *(const uint4*)&Ys[nl * 256 + 4 * kq];
        const uint4 w4 = *(const uint4*)&Ws[c * 256 + 4 * kq];
        a0 = dot2(y4.x, w4.x, a0);
        a1 = dot2(y4.y, w4.y, a1);
        a0 = dot2(y4.z, w4.z, a0);
        a1 = dot2(y4.w, w4.w, a1);
      }
      out[(size_t)(nb * 64 + nl) * 6 + c] = a0 + a1 + bm3[c];
    }
  }
}

// ---------------------------------------------------------------------------
extern "C" void kernel_launch(void* const* d_in, const int* in_sizes, int n_in,
                              void* d_out, int out_size, void* d_ws,
                              size_t ws_size, hipStream_t stream) {
  (void)in_sizes; (void)n_in; (void)out_size; (void)ws_size;
  const float* cnn  = (const float*)d_in[0];
  const float* gaze = (const float*)d_in[1];
  const float* W_lh = (const float*)d_in[2];
  const float* b_lh = (const float*)d_in[3];
  const float* W_cn = (const float*)d_in[4];
  const float* b_cn = (const float*)d_in[5];
  const float* w_wt = (const float*)d_in[6];
  const float* Wih  = (const float*)d_in[7];
  const float* Whh  = (const float*)d_in[8];
  const float* bih  = (const float*)d_in[9];
  const float* bhh  = (const float*)d_in[10];
  const float* Wh1  = (const float*)d_in[11];
  const float* bh1  = (const float*)d_in[12];
  const float* Wh2  = (const float*)d_in[13];
  const float* bh2  = (const float*)d_in[14];
  const float* Wc1  = (const float*)d_in[15];
  const float* bc1  = (const float*)d_in[16];
  const float* Wc2  = (const float*)d_in[17];
  const float* bc2  = (const float*)d_in[18];
  const float* Wm1  = (const float*)d_in[19];
  const float* bm1  = (const float*)d_in[20];
  const float* Wm2  = (const float*)d_in[21];
  const float* bm2  = (const float*)d_in[22];
  const float* Wm3  = (const float*)d_in[23];
  const float* bm3  = (const float*)d_in[24];
  float* out = (float*)d_out;

  unsigned* W = (unsigned*)d_ws;
  float* Wf = (float*)d_ws;
  // workspace offsets in dwords
  const size_t O_xg  = 0;                    // [31][64][1024] f32
  const size_t O_w4  = 2031616;              // [4][512][64]   u32 (h2)
  const size_t O_gb  = O_w4 + 131072;        // [2][64][4][256] f32
  const size_t O_fl  = O_gb + 131072;        // [64][4]        int
  const size_t O_HH  = O_fl + 256;           // [33][64][256]  f32
  const size_t O_c0  = O_HH + 540672;        // [64][256]      f32
  const size_t O_Hl  = O_c0 + 16384;         // [32][64][128]  f32
  const size_t O_z   = O_Hl + 262144;        // [32][64][36]   f32
  const size_t O_fc  = O_z + 73728;          // [2048][512]    f32
  const size_t O_y1  = O_fc + 1048576;       // [2048][256]    u32 (h2)
  const size_t O_y2  = O_y1 + 524288;        // [2048][256]    u32 (h2)
  const size_t O_wcn = O_y2 + 524288;        // [128][128]     u32
  const size_t O_wlh = O_wcn + 16384;
  const size_t O_wm1 = O_wlh + 16384;        // [512][256]
  const size_t O_wm2 = O_wm1 + 131072;
  const size_t O_wm3 = O_wm2 + 131072;       // [6][256]

  float* xg  = Wf + O_xg;
  float* HH  = Wf + O_HH;
  float* c0f = Wf + O_c0;
  float* Hlf = Wf + O_Hl;
  float* zf  = Wf + O_z;
  float* fcf = Wf + O_fc;
  float* gbf = Wf + O_gb;
  int* flg   = (int*)(Wf + O_fl);

  // --- prepacking (independent) ---
  k_pack_w4<<<512, 256, 0, stream>>>(Whh, W + O_w4);
  k_zero<<<1, 256, 0, stream>>>(flg);
  k_packh2<<<64, 256, 0, stream>>>(W_cn, W + O_wcn, 16384);
  k_packh2<<<64, 256, 0, stream>>>(W_lh, W + O_wlh, 16384);
  k_packh2<<<512, 256, 0, stream>>>(Wm1, W + O_wm1, 131072);
  k_packh2<<<512, 256, 0, stream>>>(Wm2, W + O_wm2, 131072);
  k_packh2<<<6, 256, 0, stream>>>(Wm3, W + O_wm3, 1536);
  k_xg<<<7936, 256, 0, stream>>>(gaze, Wih, bih, bhh, xg);
  k_init<<<64, 256, 0, stream>>>(gaze, Wh1, bh1, Wh2, bh2, Wc1, bc1, Wc2, bc2,
                                 HH, c0f);
  // --- the sequential chain: 64 chains x 4 cooperating blocks ---
  k_lstm4<<<256, 512, 0, stream>>>(xg, W + O_w4, c0f, HH, gbf, flg);
  // --- batched attention ---
  k_hl<<<32, 256, 0, stream>>>(HH, W + O_wlh, b_lh, Hlf);
  k_att_z<<<576, 256, 0, stream>>>(cnn, W + O_wcn, b_cn, Hlf, w_wt, zf);
  k_att_sf<<<2048, 256, 0, stream>>>(cnn, zf, HH, fcf);
  // --- batched MLP ---
  k_mlp<0><<<128, 256, 0, stream>>>((const void*)fcf, W + O_wm1, bm1, W + O_y1);
  k_mlp<1><<<128, 256, 0, stream>>>((const void*)(W + O_y1), W + O_wm2, bm2, W + O_y2);
  k_mlp3<<<32, 256, 0, stream>>>(W + O_y2, W + O_wm3, bm3, out);
}

// Round 8
// 2471.042 us; speedup vs baseline: 7.1540x; 7.1540x over previous
//
#include <hip/hip_runtime.h>
#include <math.h>

// ---------------------------------------------------------------------------
// SpatialAttentionModel on MI355X.
// (1) init h0/c0, (2) precompute LSTM input projections, (3) ONE sequential
// LSTM chain (497 steps) recording h at frame boundaries, (4) batched
// attention, (5) batched 3-layer MLP.
// R8: revert R7's 4-block split (agent-scope sync = 35us/step, dead).
// k_lstm now 256 threads/block, 1 block/chain, 64 CUs: thread r owns ALL
// FOUR gate rows of hidden unit r. LDS (147KB) forces 1 block/CU = 1
// wave/SIMD, so the compiler's occupancy analysis itself allows 512
// VGPRs/thread: 384 persistent weight dwords (pairs 32..127 x 4 rows,
// asm-pinned scalars) + pairs 0..31 from LDS. Thread-local c/h update,
// double-buffered h2l -> ONE barrier/step.
// ---------------------------------------------------------------------------

typedef _Float16 h2_t __attribute__((ext_vector_type(2)));

#if __has_builtin(__builtin_amdgcn_fdot2)
#define HAVE_FDOT2 1
#else
#define HAVE_FDOT2 0
#endif

__device__ __forceinline__ float dot2(unsigned w, unsigned h, float acc) {
#if HAVE_FDOT2
  return __builtin_amdgcn_fdot2(__builtin_bit_cast(h2_t, w),
                                __builtin_bit_cast(h2_t, h), acc, false);
#else
  h2_t a = __builtin_bit_cast(h2_t, w);
  h2_t b = __builtin_bit_cast(h2_t, h);
  return acc + (float)a[0] * (float)b[0] + (float)a[1] * (float)b[1];
#endif
}

__device__ __forceinline__ unsigned pack2(float a, float b) {
  h2_t p;
  p[0] = (_Float16)a;
  p[1] = (_Float16)b;
  return __builtin_bit_cast(unsigned, p);
}

__device__ __forceinline__ float sigmoid_f(float x) {
  return __builtin_amdgcn_rcpf(1.f + __expf(-x));
}
__device__ __forceinline__ float tanh_f(float x) {
  return 1.f - 2.f * __builtin_amdgcn_rcpf(1.f + __expf(2.f * x));
}

// ---------------------------------------------------------------------------
// Pack Whh into the LSTM kernel's two layouts (same as R6):
//  wv_pack (uint4 view): [24][1024] quads; quad (m,row) = pairs 32+4m..32+4m+3
//  of gate row `row`.
//  wlds_pack[row][p] (p<32): pairs 0..31 of every row (read from LDS).
__global__ void k_pack_wv(const float* __restrict__ Whh,
                          unsigned* __restrict__ wv_pack,
                          unsigned* __restrict__ wlds_pack) {
  const int idx = blockIdx.x * 256 + threadIdx.x;  // < 131072
  if (idx < 98304) {
    const int quad = idx >> 2, j = idx & 3;
    const int m = quad >> 10, row = quad & 1023;  // m < 24
    const int pair = 32 + 4 * m + j;
    wv_pack[idx] = pack2(Whh[row * 256 + 2 * pair], Whh[row * 256 + 2 * pair + 1]);
  } else {
    const int j = idx - 98304;  // < 32768
    const int row = j >> 5, pair = j & 31;
    wlds_pack[j] = pack2(Whh[row * 256 + 2 * pair], Whh[row * 256 + 2 * pair + 1]);
  }
}

// Generic f32 -> packed-f16-pair converter (contiguous rows, even cols).
__global__ void k_packh2(const float* __restrict__ src,
                         unsigned* __restrict__ dst, int n) {
  const int i = blockIdx.x * 256 + threadIdx.x;
  if (i < n) dst[i] = pack2(src[2 * i], src[2 * i + 1]);
}

// xg4[t][b][r][q] = gaze[b,t,:]·Wih[q*256+r,:] + bih[.] + bhh[.]
// (unit-major, gate-minor: one float4 per (t,b,unit)).
__global__ void k_xg(const float* __restrict__ gaze,
                     const float* __restrict__ Wih,
                     const float* __restrict__ bih,
                     const float* __restrict__ bhh,
                     float* __restrict__ xg4) {
  const int idx = blockIdx.x * 256 + threadIdx.x;
  if (idx >= 31 * 64 * 1024) return;
  const int q = idx & 3;
  const int r = (idx >> 2) & 255;
  const int b = (idx >> 10) & 63;
  const int t = idx >> 16;
  const int j = q * 256 + r;
  const float* gz = gaze + (b * 32 + t) * 3;
  xg4[idx] = gz[0] * Wih[j * 3 + 0] + gz[1] * Wih[j * 3 + 1] +
             gz[2] * Wih[j * 3 + 2] + bih[j] + bhh[j];
}

// h0/c0: h = tanh(tanh( tanh(mg@Wh1.T+bh1) @ Wh2.T + bh2 )), same for c.
__global__ void k_init(const float* __restrict__ gaze,
                       const float* __restrict__ Wh1, const float* __restrict__ bh1,
                       const float* __restrict__ Wh2, const float* __restrict__ bh2,
                       const float* __restrict__ Wc1, const float* __restrict__ bc1,
                       const float* __restrict__ Wc2, const float* __restrict__ bc2,
                       float* __restrict__ HH, float* __restrict__ c0) {
  const int b = blockIdx.x;
  const int tid = threadIdx.x;  // 256
  __shared__ float mg[3];
  __shared__ float t1h[256], t1c[256];
  if (tid < 3) {
    float s = 0.f;
    for (int t = 0; t < 32; t++) s += gaze[(b * 32 + t) * 3 + tid];
    mg[tid] = s * (1.f / 32.f);
  }
  __syncthreads();
  {
    float a = mg[0] * Wh1[tid * 3 + 0] + mg[1] * Wh1[tid * 3 + 1] +
              mg[2] * Wh1[tid * 3 + 2] + bh1[tid];
    t1h[tid] = tanhf(a);
    float c = mg[0] * Wc1[tid * 3 + 0] + mg[1] * Wc1[tid * 3 + 1] +
              mg[2] * Wc1[tid * 3 + 2] + bc1[tid];
    t1c[tid] = tanhf(c);
  }
  __syncthreads();
  float s1 = bh2[tid], s2 = bc2[tid];
  for (int k = 0; k < 256; k++) {
    s1 += t1h[k] * Wh2[tid * 256 + k];
    s2 += t1c[k] * Wc2[tid * 256 + k];
  }
  HH[b * 256 + tid] = tanhf(tanhf(s1));  // HH[0][b][k]
  c0[b * 256 + tid] = tanhf(tanhf(s2));
}

// ---------------------------------------------------------------------------
// The sequential LSTM chain. One block of 256 threads per batch element.
// Thread r owns hidden unit r = all four gate rows {r, 256+r, 512+r, 768+r}.
// Weights: pairs 32..127 of the 4 rows = 96 pinned uint4s (384 VGPRs);
// pairs 0..31 of all 1024 rows in LDS (stride-36, 0 conflicts measured).
// h: double-buffered packed-f16 h2l[2][128] -> one barrier per step.
// c/h update is thread-local (owns all 4 gates of its unit).
__global__ __launch_bounds__(256) void k_lstm(
    const float* __restrict__ xg4, const unsigned* __restrict__ wv_pack,
    const unsigned* __restrict__ wlds_pack, const float* __restrict__ c0,
    float* __restrict__ HH) {
  const int b = blockIdx.x;
  const int tid = threadIdx.x;  // hidden unit r
  __shared__ __align__(16) unsigned wlds[1024 * 36];  // 147456 B
  __shared__ __align__(16) unsigned h2l[2][128];

  for (int i = tid; i < 1024 * 32; i += 256) {
    const int row = i >> 5, p = i & 31;
    wlds[row * 36 + p] = wlds_pack[i];
  }

  // 96 quads = 384 persistent dwords: quad (G,M) = pairs 32+4M.. of row
  // 256G + tid.
  const uint4* wqbase = (const uint4*)wv_pack + tid;
#define DECLQ(G, M)                                                        \
  const uint4 q##G##_##M = wqbase[(M) * 1024 + 256 * (G)];                 \
  unsigned w##G##_##M##x = q##G##_##M.x, w##G##_##M##y = q##G##_##M.y,     \
           w##G##_##M##z = q##G##_##M.z, w##G##_##M##w = q##G##_##M.w;
#define FOR24(F, G)                                                       \
  F(G, 0) F(G, 1) F(G, 2) F(G, 3) F(G, 4) F(G, 5) F(G, 6) F(G, 7)        \
  F(G, 8) F(G, 9) F(G, 10) F(G, 11) F(G, 12) F(G, 13) F(G, 14) F(G, 15)  \
  F(G, 16) F(G, 17) F(G, 18) F(G, 19) F(G, 20) F(G, 21) F(G, 22) F(G, 23)
  FOR24(DECLQ, 0) FOR24(DECLQ, 1) FOR24(DECLQ, 2) FOR24(DECLQ, 3)
#undef DECLQ
  // Pin all 384 scalars (scalar "+v" ties: supported; keeps allocator from
  // spilling/sinking them back to memory).
#define PIN4(G, M) \
  "+v"(w##G##_##M##x), "+v"(w##G##_##M##y), "+v"(w##G##_##M##z), "+v"(w##G##_##M##w)
  asm volatile("" : PIN4(0, 0), PIN4(0, 1), PIN4(0, 2), PIN4(0, 3), PIN4(0, 4), PIN4(0, 5));
  asm volatile("" : PIN4(0, 6), PIN4(0, 7), PIN4(0, 8), PIN4(0, 9), PIN4(0, 10), PIN4(0, 11));
  asm volatile("" : PIN4(0, 12), PIN4(0, 13), PIN4(0, 14), PIN4(0, 15), PIN4(0, 16), PIN4(0, 17));
  asm volatile("" : PIN4(0, 18), PIN4(0, 19), PIN4(0, 20), PIN4(0, 21), PIN4(0, 22), PIN4(0, 23));
  asm volatile("" : PIN4(1, 0), PIN4(1, 1), PIN4(1, 2), PIN4(1, 3), PIN4(1, 4), PIN4(1, 5));
  asm volatile("" : PIN4(1, 6), PIN4(1, 7), PIN4(1, 8), PIN4(1, 9), PIN4(1, 10), PIN4(1, 11));
  asm volatile("" : PIN4(1, 12), PIN4(1, 13), PIN4(1, 14), PIN4(1, 15), PIN4(1, 16), PIN4(1, 17));
  asm volatile("" : PIN4(1, 18), PIN4(1, 19), PIN4(1, 20), PIN4(1, 21), PIN4(1, 22), PIN4(1, 23));
  asm volatile("" : PIN4(2, 0), PIN4(2, 1), PIN4(2, 2), PIN4(2, 3), PIN4(2, 4), PIN4(2, 5));
  asm volatile("" : PIN4(2, 6), PIN4(2, 7), PIN4(2, 8), PIN4(2, 9), PIN4(2, 10), PIN4(2, 11));
  asm volatile("" : PIN4(2, 12), PIN4(2, 13), PIN4(2, 14), PIN4(2, 15), PIN4(2, 16), PIN4(2, 17));
  asm volatile("" : PIN4(2, 18), PIN4(2, 19), PIN4(2, 20), PIN4(2, 21), PIN4(2, 22), PIN4(2, 23));
  asm volatile("" : PIN4(3, 0), PIN4(3, 1), PIN4(3, 2), PIN4(3, 3), PIN4(3, 4), PIN4(3, 5));
  asm volatile("" : PIN4(3, 6), PIN4(3, 7), PIN4(3, 8), PIN4(3, 9), PIN4(3, 10), PIN4(3, 11));
  asm volatile("" : PIN4(3, 12), PIN4(3, 13), PIN4(3, 14), PIN4(3, 15), PIN4(3, 16), PIN4(3, 17));
  asm volatile("" : PIN4(3, 18), PIN4(3, 19), PIN4(3, 20), PIN4(3, 21), PIN4(3, 22), PIN4(3, 23));
#undef PIN4

  float cst = c0[b * 256 + tid];
  ((_Float16*)h2l[0])[tid] = (_Float16)HH[b * 256 + tid];
  __syncthreads();

  const unsigned* wA0 = &wlds[(tid)*36];
  const unsigned* wA1 = &wlds[(tid + 256) * 36];
  const unsigned* wA2 = &wlds[(tid + 512) * 36];
  const unsigned* wA3 = &wlds[(tid + 768) * 36];

  int s = 0;
  float hval = 0.f;
  for (int frame = 0; frame < 32; frame++) {
    const int L = frame ? frame : 1;
    for (int t = 0; t < L; t++) {
      const float4 xq =
          *(const float4*)&xg4[(((size_t)t * 64 + b) * 256 + tid) * 4];
      const unsigned* hb = h2l[s & 1];
      float ai = 0.f, af = 0.f, ag = 0.f, ao = 0.f;
      // pairs 0..31 from LDS weights
#pragma unroll
      for (int q = 0; q < 8; q++) {
        const uint4 h4 = *(const uint4*)&hb[4 * q];
        const uint4 a0 = *(const uint4*)&wA0[4 * q];
        const uint4 a1 = *(const uint4*)&wA1[4 * q];
        const uint4 a2 = *(const uint4*)&wA2[4 * q];
        const uint4 a3 = *(const uint4*)&wA3[4 * q];
        ai = dot2(a0.x, h4.x, ai); ai = dot2(a0.y, h4.y, ai);
        ai = dot2(a0.z, h4.z, ai); ai = dot2(a0.w, h4.w, ai);
        af = dot2(a1.x, h4.x, af); af = dot2(a1.y, h4.y, af);
        af = dot2(a1.z, h4.z, af); af = dot2(a1.w, h4.w, af);
        ag = dot2(a2.x, h4.x, ag); ag = dot2(a2.y, h4.y, ag);
        ag = dot2(a2.z, h4.z, ag); ag = dot2(a2.w, h4.w, ag);
        ao = dot2(a3.x, h4.x, ao); ao = dot2(a3.y, h4.y, ao);
        ao = dot2(a3.z, h4.z, ao); ao = dot2(a3.w, h4.w, ao);
      }
      // pairs 32..127 from the pinned quads
#define DOTM(M)                                                \
  {                                                            \
    const uint4 h4 = *(const uint4*)&hb[32 + 4 * (M)];         \
    ai = dot2(w0_##M##x, h4.x, ai); ai = dot2(w0_##M##y, h4.y, ai); \
    ai = dot2(w0_##M##z, h4.z, ai); ai = dot2(w0_##M##w, h4.w, ai); \
    af = dot2(w1_##M##x, h4.x, af); af = dot2(w1_##M##y, h4.y, af); \
    af = dot2(w1_##M##z, h4.z, af); af = dot2(w1_##M##w, h4.w, af); \
    ag = dot2(w2_##M##x, h4.x, ag); ag = dot2(w2_##M##y, h4.y, ag); \
    ag = dot2(w2_##M##z, h4.z, ag); ag = dot2(w2_##M##w, h4.w, ag); \
    ao = dot2(w3_##M##x, h4.x, ao); ao = dot2(w3_##M##y, h4.y, ao); \
    ao = dot2(w3_##M##z, h4.z, ao); ao = dot2(w3_##M##w, h4.w, ao); \
  }
      DOTM(0) DOTM(1) DOTM(2) DOTM(3) DOTM(4) DOTM(5)
      DOTM(6) DOTM(7) DOTM(8) DOTM(9) DOTM(10) DOTM(11)
      DOTM(12) DOTM(13) DOTM(14) DOTM(15) DOTM(16) DOTM(17)
      DOTM(18) DOTM(19) DOTM(20) DOTM(21) DOTM(22) DOTM(23)
#undef DOTM
      // thread-local gate combine + state update
      const float i_ = sigmoid_f(ai + xq.x);
      const float f_ = sigmoid_f(af + xq.y);
      const float g_ = tanh_f(ag + xq.z);
      const float o_ = sigmoid_f(ao + xq.w);
      cst = f_ * cst + i_ * g_;
      hval = o_ * tanh_f(cst);
      ((_Float16*)h2l[(s + 1) & 1])[tid] = (_Float16)hval;
      s++;
      __syncthreads();  // write buffer visible; it is next step's read buffer
    }
    HH[((frame + 1) * 64 + b) * 256 + tid] = hval;
  }
}

// Hl[i][b][p] = HH[i][b]·W_lh[p] + b_lh[p]. One block per frame.
__global__ void k_hl(const float* __restrict__ HH,
                     const unsigned* __restrict__ wlh_h2,
                     const float* __restrict__ blh, float* __restrict__ Hl) {
  const int i = blockIdx.x;
  const int tid = threadIdx.x;  // 256
  __shared__ __align__(16) unsigned Ah[64 * 132];
  __shared__ __align__(16) unsigned Bh[128 * 132];
  for (int idx = tid; idx < 64 * 128; idx += 256) {
    const int r = idx >> 7, kp = idx & 127;
    const float* s = HH + ((size_t)(i * 64 + r)) * 256 + 2 * kp;
    Ah[r * 132 + kp] = pack2(s[0], s[1]);
  }
  for (int idx = tid; idx < 128 * 128; idx += 256) {
    const int o = idx >> 7, kp = idx & 127;
    Bh[o * 132 + kp] = wlh_h2[o * 128 + kp];
  }
  __syncthreads();
  const int ry = tid >> 4, px = tid & 15;
  float acc[4][8];
#pragma unroll
  for (int k = 0; k < 4; k++)
#pragma unroll
    for (int j = 0; j < 8; j++) acc[k][j] = 0.f;
  for (int kb = 0; kb < 32; kb++) {
    uint4 a4[4], b4[8];
#pragma unroll
    for (int k = 0; k < 4; k++) a4[k] = *(const uint4*)&Ah[(16 * k + ry) * 132 + 4 * kb];
#pragma unroll
    for (int j = 0; j < 8; j++) b4[j] = *(const uint4*)&Bh[(16 * j + px) * 132 + 4 * kb];
#pragma unroll
    for (int k = 0; k < 4; k++)
#pragma unroll
      for (int j = 0; j < 8; j++) {
        acc[k][j] = dot2(a4[k].x, b4[j].x, acc[k][j]);
        acc[k][j] = dot2(a4[k].y, b4[j].y, acc[k][j]);
        acc[k][j] = dot2(a4[k].z, b4[j].z, acc[k][j]);
        acc[k][j] = dot2(a4[k].w, b4[j].w, acc[k][j]);
      }
  }
#pragma unroll
  for (int k = 0; k < 4; k++)
#pragma unroll
    for (int j = 0; j < 8; j++)
      Hl[(i * 64 + 16 * k + ry) * 128 + 16 * j + px] = acc[k][j] + blh[16 * j + px];
}

// Fused Vp GEMM + z. Rows = flattened (b,g) within frame i (2304 rows, tiles
// of 128). z[b,g] = sum_p w[p]*tanh(Hl[b,p] + Vp[b,g,p]).
__global__ void k_att_z(const float* __restrict__ cnn,
                        const unsigned* __restrict__ wcn_h2,
                        const float* __restrict__ bcn,
                        const float* __restrict__ Hl,
                        const float* __restrict__ wwt,
                        float* __restrict__ zbuf) {
  const int bid = blockIdx.x;  // 576 = 32 frames * 18 row tiles
  const int i = bid / 18, rt = bid - 18 * i;
  const int tid = threadIdx.x;  // 256
  const int r0 = rt * 128;
  __shared__ __align__(16) unsigned As[128 * 132];
  __shared__ __align__(16) unsigned Bs[128 * 132];
  __shared__ float zpart[128 * 16];
  __shared__ float Hls[5 * 128];
  __shared__ float wws[128];
  __shared__ float bcs[128];

  for (int idx = tid; idx < 128 * 128; idx += 256) {
    const int r = idx >> 7, kp = idx & 127;
    const int R = r0 + r;
    const int b = R / 36, g = R - b * 36;
    const float* src = cnn + (((size_t)b * 32 + i) * 36 + g) * 256 + 2 * kp;
    As[r * 132 + kp] = pack2(src[0], src[1]);
  }
  for (int idx = tid; idx < 128 * 128; idx += 256) {
    const int o = idx >> 7, kp = idx & 127;
    Bs[o * 132 + kp] = wcn_h2[o * 128 + kp];
  }
  const int bmin = r0 / 36;
  for (int idx = tid; idx < 5 * 128; idx += 256) {
    const int bb = bmin + (idx >> 7);
    if (bb < 64) Hls[idx] = Hl[(i * 64 + bb) * 128 + (idx & 127)];
  }
  if (tid < 128) {
    wws[tid] = wwt[tid];
    bcs[tid] = bcn[tid];
  }
  __syncthreads();

  const int ry = tid >> 4, px = tid & 15;
  float acc[8][8];
#pragma unroll
  for (int k = 0; k < 8; k++)
#pragma unroll
    for (int j = 0; j < 8; j++) acc[k][j] = bcs[16 * j + px];
  for (int kb = 0; kb < 32; kb++) {
    uint4 a4[8], b4[8];
#pragma unroll
    for (int k = 0; k < 8; k++) a4[k] = *(const uint4*)&As[(16 * k + ry) * 132 + 4 * kb];
#pragma unroll
    for (int j = 0; j < 8; j++) b4[j] = *(const uint4*)&Bs[(16 * j + px) * 132 + 4 * kb];
#pragma unroll
    for (int k = 0; k < 8; k++)
#pragma unroll
      for (int j = 0; j < 8; j++) {
        acc[k][j] = dot2(a4[k].x, b4[j].x, acc[k][j]);
        acc[k][j] = dot2(a4[k].y, b4[j].y, acc[k][j]);
        acc[k][j] = dot2(a4[k].z, b4[j].z, acc[k][j]);
        acc[k][j] = dot2(a4[k].w, b4[j].w, acc[k][j]);
      }
  }
#pragma unroll
  for (int k = 0; k < 8; k++) {
    const int r = 16 * k + ry;
    const int R = r0 + r;
    const int b = R / 36;
    const float* HlRow = &Hls[(b - bmin) * 128];
    float zp = 0.f;
#pragma unroll
    for (int j = 0; j < 8; j++) {
      const int po = 16 * j + px;
      zp += wws[po] * tanh_f(HlRow[po] + acc[k][j]);
    }
    zpart[r * 16 + px] = zp;
  }
  __syncthreads();
  if (tid < 128) {
    float z = 0.f;
#pragma unroll
    for (int x = 0; x < 16; x++) z += zpart[tid * 16 + x];
    const int R = r0 + tid;
    const int b = R / 36, g = R - b * 36;
    zbuf[(i * 64 + b) * 36 + g] = z;
  }
}

// Scrambled softmax + weighted V sum; builds fc = [spatial_feat | h_next].
__global__ void k_att_sf(const float* __restrict__ cnn,
                         const float* __restrict__ zbuf,
                         const float* __restrict__ HH,
                         float* __restrict__ fc) {
  const int bid = blockIdx.x;  // 2048 = i*64 + b
  const int i = bid >> 6, b = bid & 63;
  const int tid = threadIdx.x;  // 256
  __shared__ float zl[36];
  __shared__ float el[40];
  __shared__ float red[1];
  if (tid < 36) {
    const int idx = b * 36 + tid;  // scramble: z.T.reshape(64,36)
    zl[tid] = zbuf[(i * 64 + (idx & 63)) * 36 + (idx >> 6)];
  }
  __syncthreads();
  if (tid == 0) {
    float m = zl[0];
    for (int g = 1; g < 36; g++) m = fmaxf(m, zl[g]);
    float s = 0.f;
    for (int g = 0; g < 36; g++) {
      const float e = __expf(zl[g] - m);
      el[g] = e;
      s += e;
    }
    red[0] = 1.f / s;
  }
  __syncthreads();
  const float inv = red[0];
  float accv = 0.f;
  const float* Vb = cnn + (((size_t)b * 32 + i) * 36) * 256 + tid;
#pragma unroll 4
  for (int g = 0; g < 36; g++) accv += el[g] * Vb[g * 256];
  fc[(size_t)bid * 512 + tid] = accv * inv;
  fc[(size_t)bid * 512 + 256 + tid] = HH[((i + 1) * 64 + b) * 256 + tid];
}

// MLP layers 1/2: (2048,512)@(512,512)+b, output packed f16 pairs.
template <int SRCMODE>  // 0: f32 src (fc), 1: packed-h2 src
__global__ void k_mlp(const void* __restrict__ src,
                      const unsigned* __restrict__ wh2,
                      const float* __restrict__ bias,
                      unsigned* __restrict__ dst) {
  const int bid = blockIdx.x;  // 128 = 32 n-tiles * 4 o-tiles
  const int nb = bid >> 2, ob = bid & 3;
  const int n0 = nb * 64, o0 = ob * 128;
  const int tid = threadIdx.x;
  __shared__ __align__(16) unsigned As[64 * 132];
  __shared__ __align__(16) unsigned Bs[128 * 132];
  const int ry = tid >> 4, px = tid & 15;
  float acc[4][8];
#pragma unroll
  for (int k = 0; k < 4; k++)
#pragma unroll
    for (int m = 0; m < 8; m++)
      acc[k][m] = bias[o0 + 32 * (m >> 1) + 2 * px + (m & 1)];
  for (int kc = 0; kc < 2; kc++) {
    __syncthreads();
    for (int idx = tid; idx < 64 * 128; idx += 256) {
      const int r = idx >> 7, kp = idx & 127;
      if (SRCMODE == 0) {
        const float* s = (const float*)src + ((size_t)(n0 + r)) * 512 + kc * 256 + 2 * kp;
        As[r * 132 + kp] = pack2(s[0], s[1]);
      } else {
        As[r * 132 + kp] = ((const unsigned*)src)[((size_t)(n0 + r)) * 256 + kc * 128 + kp];
      }
    }
    for (int idx = tid; idx < 128 * 128; idx += 256) {
      const int o = idx >> 7, kp = idx & 127;
      Bs[o * 132 + kp] = wh2[((size_t)(o0 + o)) * 256 + kc * 128 + kp];
    }
    __syncthreads();
    for (int kb = 0; kb < 32; kb++) {
      uint4 a4[4], b4[8];
#pragma unroll
      for (int k = 0; k < 4; k++)
        a4[k] = *(const uint4*)&As[(16 * k + ry) * 132 + 4 * kb];
#pragma unroll
      for (int m = 0; m < 8; m++)
        b4[m] = *(const uint4*)&Bs[(32 * (m >> 1) + 2 * px + (m & 1)) * 132 + 4 * kb];
#pragma unroll
      for (int k = 0; k < 4; k++)
#pragma unroll
        for (int m = 0; m < 8; m++) {
          acc[k][m] = dot2(a4[k].x, b4[m].x, acc[k][m]);
          acc[k][m] = dot2(a4[k].y, b4[m].y, acc[k][m]);
          acc[k][m] = dot2(a4[k].z, b4[m].z, acc[k][m]);
          acc[k][m] = dot2(a4[k].w, b4[m].w, acc[k][m]);
        }
    }
  }
#pragma unroll
  for (int k = 0; k < 4; k++) {
    const int n = n0 + 16 * k + ry;
#pragma unroll
    for (int j = 0; j < 4; j++)
      dst[(size_t)n * 256 + (o0 >> 1) + 16 * j + px] =
          pack2(acc[k][2 * j], acc[k][2 * j + 1]);
  }
}

// Final layer: (2048,512) -> 6 classes.
__global__ void k_mlp3(const unsigned* __restrict__ y2h2,
                       const unsigned* __restrict__ wm3h2,
                       const float* __restrict__ bm3,
                       float* __restrict__ out) {
  const int nb = blockIdx.x;  // 32
  const int tid = threadIdx.x;
  __shared__ __align__(16) unsigned Ys[64 * 256];
  __shared__ __align__(16) unsigned Ws[6 * 256];
  for (int idx = tid; idx < 64 * 256; idx += 256)
    Ys[idx] = y2h2[(size_t)nb * 64 * 256 + idx];
  for (int idx = tid; idx < 6 * 256; idx += 256) Ws[idx] = wm3h2[idx];
  __syncthreads();
  for (int u = 0; u < 2; u++) {
    const int idx = tid + u * 256;
    if (idx < 384) {
      const int nl = idx / 6, c = idx - 6 * nl;
      float a0 = 0.f, a1 = 0.f;
#pragma unroll
      for (int kq = 0; kq < 64; kq++) {
        const uint4 y4 = *(const uint4*)&Ys[nl * 256 + 4 * kq];
        const uint4 w4 = *(const uint4*)&Ws[c * 256 + 4 * kq];
        a0 = dot2(y4.x, w4.x, a0);
        a1 = dot2(y4.y, w4.y, a1);
        a0 = dot2(y4.z, w4.z, a0);
        a1 = dot2(y4.w, w4.w, a1);
      }
      out[(size_t)(nb * 64 + nl) * 6 + c] = a0 + a1 + bm3[c];
    }
  }
}

// ---------------------------------------------------------------------------
extern "C" void kernel_launch(void* const* d_in, const int* in_sizes, int n_in,
                              void* d_out, int out_size, void* d_ws,
                              size_t ws_size, hipStream_t stream) {
  (void)in_sizes; (void)n_in; (void)out_size; (void)ws_size;
  const float* cnn  = (const float*)d_in[0];
  const float* gaze = (const float*)d_in[1];
  const float* W_lh = (const float*)d_in[2];
  const float* b_lh = (const float*)d_in[3];
  const float* W_cn = (const float*)d_in[4];
  const float* b_cn = (const float*)d_in[5];
  const float* w_wt = (const float*)d_in[6];
  const float* Wih  = (const float*)d_in[7];
  const float* Whh  = (const float*)d_in[8];
  const float* bih  = (const float*)d_in[9];
  const float* bhh  = (const float*)d_in[10];
  const float* Wh1  = (const float*)d_in[11];
  const float* bh1  = (const float*)d_in[12];
  const float* Wh2  = (const float*)d_in[13];
  const float* bh2  = (const float*)d_in[14];
  const float* Wc1  = (const float*)d_in[15];
  const float* bc1  = (const float*)d_in[16];
  const float* Wc2  = (const float*)d_in[17];
  const float* bc2  = (const float*)d_in[18];
  const float* Wm1  = (const float*)d_in[19];
  const float* bm1  = (const float*)d_in[20];
  const float* Wm2  = (const float*)d_in[21];
  const float* bm2  = (const float*)d_in[22];
  const float* Wm3  = (const float*)d_in[23];
  const float* bm3  = (const float*)d_in[24];
  float* out = (float*)d_out;

  unsigned* W = (unsigned*)d_ws;
  float* Wf = (float*)d_ws;
  // workspace offsets in dwords
  const size_t O_xg  = 0;                    // [31][64][256][4] f32
  const size_t O_wv  = 2031616;              // [24][1024] uint4 = 98304 u32
  const size_t O_wl  = O_wv + 98304;         // [1024][32]     u32
  const size_t O_HH  = O_wl + 32768;         // [33][64][256]  f32
  const size_t O_c0  = O_HH + 540672;        // [64][256]      f32
  const size_t O_Hl  = O_c0 + 16384;         // [32][64][128]  f32
  const size_t O_z   = O_Hl + 262144;        // [32][64][36]   f32
  const size_t O_fc  = O_z + 73728;          // [2048][512]    f32
  const size_t O_y1  = O_fc + 1048576;       // [2048][256]    u32 (h2)
  const size_t O_y2  = O_y1 + 524288;        // [2048][256]    u32 (h2)
  const size_t O_wcn = O_y2 + 524288;        // [128][128]     u32
  const size_t O_wlh = O_wcn + 16384;
  const size_t O_wm1 = O_wlh + 16384;        // [512][256]
  const size_t O_wm2 = O_wm1 + 131072;
  const size_t O_wm3 = O_wm2 + 131072;       // [6][256]

  float* xg  = Wf + O_xg;
  float* HH  = Wf + O_HH;
  float* c0f = Wf + O_c0;
  float* Hlf = Wf + O_Hl;
  float* zf  = Wf + O_z;
  float* fcf = Wf + O_fc;

  // --- prepacking (independent) ---
  k_pack_wv<<<512, 256, 0, stream>>>(Whh, W + O_wv, W + O_wl);
  k_packh2<<<64, 256, 0, stream>>>(W_cn, W + O_wcn, 16384);
  k_packh2<<<64, 256, 0, stream>>>(W_lh, W + O_wlh, 16384);
  k_packh2<<<512, 256, 0, stream>>>(Wm1, W + O_wm1, 131072);
  k_packh2<<<512, 256, 0, stream>>>(Wm2, W + O_wm2, 131072);
  k_packh2<<<6, 256, 0, stream>>>(Wm3, W + O_wm3, 1536);
  k_xg<<<7936, 256, 0, stream>>>(gaze, Wih, bih, bhh, xg);
  k_init<<<64, 256, 0, stream>>>(gaze, Wh1, bh1, Wh2, bh2, Wc1, bc1, Wc2, bc2,
                                 HH, c0f);
  // --- the sequential chain ---
  k_lstm<<<64, 256, 0, stream>>>(xg, W + O_wv, W + O_wl, c0f, HH);
  // --- batched attention ---
  k_hl<<<32, 256, 0, stream>>>(HH, W + O_wlh, b_lh, Hlf);
  k_att_z<<<576, 256, 0, stream>>>(cnn, W + O_wcn, b_cn, Hlf, w_wt, zf);
  k_att_sf<<<2048, 256, 0, stream>>>(cnn, zf, HH, fcf);
  // --- batched MLP ---
  k_mlp<0><<<128, 256, 0, stream>>>((const void*)fcf, W + O_wm1, bm1, W + O_y1);
  k_mlp<1><<<128, 256, 0, stream>>>((const void*)(W + O_y1), W + O_wm2, bm2, W + O_y2);
  k_mlp3<<<32, 256, 0, stream>>>(W + O_y2, W + O_wm3, bm3, out);
}

// Round 9
// 1988.637 us; speedup vs baseline: 8.8895x; 1.2426x over previous
//
#include <hip/hip_runtime.h>
#include <math.h>

// ---------------------------------------------------------------------------
// SpatialAttentionModel on MI355X.
// (1) init h0/c0, (2) precompute LSTM input projections, (3) ONE sequential
// LSTM chain (497 steps) recording h at frame boundaries, (4) batched
// attention, (5) batched 3-layer MLP.
// R9: R8's VGPR_Count=256 revealed the real budget: 256 addressable VGPRs +
// 256 AGPRs (unified 512). The compiler won't spill into AGPRs on its own,
// so we pin there explicitly: per thread (owns 4 gate rows of unit r):
//   pairs 64..127 x4 rows = 256 dwords  -> AGPR  ("+a" asm pins)
//   pairs 16..63  x4 rows = 192 dwords  -> VGPR  ("+v" asm pins)
//   pairs 0..15 of all rows             -> LDS   (stride-36, 0 conflicts)
// In-loop AGPR use costs one v_accvgpr_read (2cyc) per dword - cheaper than
// any memory tier. Thread-local c/h update, 1 barrier/step (R8 structure).
// ---------------------------------------------------------------------------

typedef _Float16 h2_t __attribute__((ext_vector_type(2)));

#if __has_builtin(__builtin_amdgcn_fdot2)
#define HAVE_FDOT2 1
#else
#define HAVE_FDOT2 0
#endif

__device__ __forceinline__ float dot2(unsigned w, unsigned h, float acc) {
#if HAVE_FDOT2
  return __builtin_amdgcn_fdot2(__builtin_bit_cast(h2_t, w),
                                __builtin_bit_cast(h2_t, h), acc, false);
#else
  h2_t a = __builtin_bit_cast(h2_t, w);
  h2_t b = __builtin_bit_cast(h2_t, h);
  return acc + (float)a[0] * (float)b[0] + (float)a[1] * (float)b[1];
#endif
}

__device__ __forceinline__ unsigned pack2(float a, float b) {
  h2_t p;
  p[0] = (_Float16)a;
  p[1] = (_Float16)b;
  return __builtin_bit_cast(unsigned, p);
}

__device__ __forceinline__ float sigmoid_f(float x) {
  return __builtin_amdgcn_rcpf(1.f + __expf(-x));
}
__device__ __forceinline__ float tanh_f(float x) {
  return 1.f - 2.f * __builtin_amdgcn_rcpf(1.f + __expf(2.f * x));
}

// ---------------------------------------------------------------------------
// Pack Whh into the LSTM kernel's two layouts:
//  wv_pack (uint4 view): [28][1024] quads; quad (m,row) = pairs 16+4m..19+4m
//  of gate row `row` (m<28 covers pairs 16..127).
//  wlds_pack[row][p] (p<16): pairs 0..15 of every row (read from LDS).
__global__ void k_pack_wv(const float* __restrict__ Whh,
                          unsigned* __restrict__ wv_pack,
                          unsigned* __restrict__ wlds_pack) {
  const int idx = blockIdx.x * 256 + threadIdx.x;  // < 131072
  if (idx < 114688) {
    const int quad = idx >> 2, j = idx & 3;
    const int m = quad >> 10, row = quad & 1023;  // m < 28
    const int pair = 16 + 4 * m + j;
    wv_pack[idx] = pack2(Whh[row * 256 + 2 * pair], Whh[row * 256 + 2 * pair + 1]);
  } else {
    const int j = idx - 114688;  // < 16384
    const int row = j >> 4, pair = j & 15;
    wlds_pack[j] = pack2(Whh[row * 256 + 2 * pair], Whh[row * 256 + 2 * pair + 1]);
  }
}

// Generic f32 -> packed-f16-pair converter (contiguous rows, even cols).
__global__ void k_packh2(const float* __restrict__ src,
                         unsigned* __restrict__ dst, int n) {
  const int i = blockIdx.x * 256 + threadIdx.x;
  if (i < n) dst[i] = pack2(src[2 * i], src[2 * i + 1]);
}

// xg4[t][b][r][q] = gaze[b,t,:]·Wih[q*256+r,:] + bih[.] + bhh[.]
// (unit-major, gate-minor: one float4 per (t,b,unit)).
__global__ void k_xg(const float* __restrict__ gaze,
                     const float* __restrict__ Wih,
                     const float* __restrict__ bih,
                     const float* __restrict__ bhh,
                     float* __restrict__ xg4) {
  const int idx = blockIdx.x * 256 + threadIdx.x;
  if (idx >= 31 * 64 * 1024) return;
  const int q = idx & 3;
  const int r = (idx >> 2) & 255;
  const int b = (idx >> 10) & 63;
  const int t = idx >> 16;
  const int j = q * 256 + r;
  const float* gz = gaze + (b * 32 + t) * 3;
  xg4[idx] = gz[0] * Wih[j * 3 + 0] + gz[1] * Wih[j * 3 + 1] +
             gz[2] * Wih[j * 3 + 2] + bih[j] + bhh[j];
}

// h0/c0: h = tanh(tanh( tanh(mg@Wh1.T+bh1) @ Wh2.T + bh2 )), same for c.
__global__ void k_init(const float* __restrict__ gaze,
                       const float* __restrict__ Wh1, const float* __restrict__ bh1,
                       const float* __restrict__ Wh2, const float* __restrict__ bh2,
                       const float* __restrict__ Wc1, const float* __restrict__ bc1,
                       const float* __restrict__ Wc2, const float* __restrict__ bc2,
                       float* __restrict__ HH, float* __restrict__ c0) {
  const int b = blockIdx.x;
  const int tid = threadIdx.x;  // 256
  __shared__ float mg[3];
  __shared__ float t1h[256], t1c[256];
  if (tid < 3) {
    float s = 0.f;
    for (int t = 0; t < 32; t++) s += gaze[(b * 32 + t) * 3 + tid];
    mg[tid] = s * (1.f / 32.f);
  }
  __syncthreads();
  {
    float a = mg[0] * Wh1[tid * 3 + 0] + mg[1] * Wh1[tid * 3 + 1] +
              mg[2] * Wh1[tid * 3 + 2] + bh1[tid];
    t1h[tid] = tanhf(a);
    float c = mg[0] * Wc1[tid * 3 + 0] + mg[1] * Wc1[tid * 3 + 1] +
              mg[2] * Wc1[tid * 3 + 2] + bc1[tid];
    t1c[tid] = tanhf(c);
  }
  __syncthreads();
  float s1 = bh2[tid], s2 = bc2[tid];
  for (int k = 0; k < 256; k++) {
    s1 += t1h[k] * Wh2[tid * 256 + k];
    s2 += t1c[k] * Wc2[tid * 256 + k];
  }
  HH[b * 256 + tid] = tanhf(tanhf(s1));  // HH[0][b][k]
  c0[b * 256 + tid] = tanhf(tanhf(s2));
}

// ---------------------------------------------------------------------------
// The sequential LSTM chain. One block of 256 threads per batch element.
// Thread r owns hidden unit r = gate rows {r, 256+r, 512+r, 768+r}.
// Weights/thread: 256 dwords AGPR-pinned + 192 VGPR-pinned + 64 from LDS.
// h: double-buffered packed-f16 h2l[2][128] -> one barrier per step.
__global__ __launch_bounds__(256) void k_lstm(
    const float* __restrict__ xg4, const unsigned* __restrict__ wv_pack,
    const unsigned* __restrict__ wlds_pack, const float* __restrict__ c0,
    float* __restrict__ HH) {
  const int b = blockIdx.x;
  const int tid = threadIdx.x;  // hidden unit r
  __shared__ __align__(16) unsigned wlds[1024 * 36];  // 147456 B
  __shared__ __align__(16) unsigned h2l[2][128];

  for (int i = tid; i < 1024 * 16; i += 256) {
    const int row = i >> 4, p = i & 15;
    wlds[row * 36 + p] = wlds_pack[i];
  }

  // Persistent weights: quad (G,M) = pairs 16+4M..19+4M of row 256G+tid.
  // M=12..27 (pairs 64..127) -> AGPR pins; M=0..11 (pairs 16..63) -> VGPR.
  // Loads and pins interleaved in <=24-operand batches to bound transient
  // VGPR pressure during init.
  const uint4* wqbase = (const uint4*)wv_pack + tid;
#define DECLQ(G, M)                                                        \
  const uint4 q##G##_##M = wqbase[(M) * 1024 + 256 * (G)];                 \
  unsigned w##G##_##M##x = q##G##_##M.x, w##G##_##M##y = q##G##_##M.y,     \
           w##G##_##M##z = q##G##_##M.z, w##G##_##M##w = q##G##_##M.w;
#define PIN4V(G, M) \
  "+v"(w##G##_##M##x), "+v"(w##G##_##M##y), "+v"(w##G##_##M##z), "+v"(w##G##_##M##w)
#define PIN4A(G, M) \
  "+a"(w##G##_##M##x), "+a"(w##G##_##M##y), "+a"(w##G##_##M##z), "+a"(w##G##_##M##w)
#define GGROUP(G)                                                           \
  DECLQ(G, 12) DECLQ(G, 13) DECLQ(G, 14) DECLQ(G, 15) DECLQ(G, 16)         \
  DECLQ(G, 17)                                                              \
  asm volatile("" : PIN4A(G, 12), PIN4A(G, 13), PIN4A(G, 14),               \
               PIN4A(G, 15), PIN4A(G, 16), PIN4A(G, 17));                   \
  DECLQ(G, 18) DECLQ(G, 19) DECLQ(G, 20) DECLQ(G, 21) DECLQ(G, 22)         \
  DECLQ(G, 23)                                                              \
  asm volatile("" : PIN4A(G, 18), PIN4A(G, 19), PIN4A(G, 20),               \
               PIN4A(G, 21), PIN4A(G, 22), PIN4A(G, 23));                   \
  DECLQ(G, 24) DECLQ(G, 25) DECLQ(G, 26) DECLQ(G, 27)                       \
  asm volatile("" : PIN4A(G, 24), PIN4A(G, 25), PIN4A(G, 26),               \
               PIN4A(G, 27));                                               \
  DECLQ(G, 0) DECLQ(G, 1) DECLQ(G, 2) DECLQ(G, 3) DECLQ(G, 4) DECLQ(G, 5)  \
  asm volatile("" : PIN4V(G, 0), PIN4V(G, 1), PIN4V(G, 2), PIN4V(G, 3),     \
               PIN4V(G, 4), PIN4V(G, 5));                                   \
  DECLQ(G, 6) DECLQ(G, 7) DECLQ(G, 8) DECLQ(G, 9) DECLQ(G, 10)             \
  DECLQ(G, 11)                                                              \
  asm volatile("" : PIN4V(G, 6), PIN4V(G, 7), PIN4V(G, 8), PIN4V(G, 9),     \
               PIN4V(G, 10), PIN4V(G, 11));
  GGROUP(0) GGROUP(1) GGROUP(2) GGROUP(3)
#undef GGROUP
#undef PIN4A
#undef PIN4V
#undef DECLQ

  float cst = c0[b * 256 + tid];
  ((_Float16*)h2l[0])[tid] = (_Float16)HH[b * 256 + tid];
  __syncthreads();

  const unsigned* wA0 = &wlds[(tid)*36];
  const unsigned* wA1 = &wlds[(tid + 256) * 36];
  const unsigned* wA2 = &wlds[(tid + 512) * 36];
  const unsigned* wA3 = &wlds[(tid + 768) * 36];

  int s = 0;
  float hval = 0.f;
  for (int frame = 0; frame < 32; frame++) {
    const int L = frame ? frame : 1;
    for (int t = 0; t < L; t++) {
      const float4 xq =
          *(const float4*)&xg4[(((size_t)t * 64 + b) * 256 + tid) * 4];
      const unsigned* hb = h2l[s & 1];
      float ai = 0.f, af = 0.f, ag = 0.f, ao = 0.f;
      // pairs 0..15 from LDS weights
#pragma unroll
      for (int q = 0; q < 4; q++) {
        const uint4 h4 = *(const uint4*)&hb[4 * q];
        const uint4 a0 = *(const uint4*)&wA0[4 * q];
        const uint4 a1 = *(const uint4*)&wA1[4 * q];
        const uint4 a2 = *(const uint4*)&wA2[4 * q];
        const uint4 a3 = *(const uint4*)&wA3[4 * q];
        ai = dot2(a0.x, h4.x, ai); ai = dot2(a0.y, h4.y, ai);
        ai = dot2(a0.z, h4.z, ai); ai = dot2(a0.w, h4.w, ai);
        af = dot2(a1.x, h4.x, af); af = dot2(a1.y, h4.y, af);
        af = dot2(a1.z, h4.z, af); af = dot2(a1.w, h4.w, af);
        ag = dot2(a2.x, h4.x, ag); ag = dot2(a2.y, h4.y, ag);
        ag = dot2(a2.z, h4.z, ag); ag = dot2(a2.w, h4.w, ag);
        ao = dot2(a3.x, h4.x, ao); ao = dot2(a3.y, h4.y, ao);
        ao = dot2(a3.z, h4.z, ao); ao = dot2(a3.w, h4.w, ao);
      }
      // pairs 16..127 from the pinned quads (V for M<12, A for M>=12)
#define DOTM(M)                                                     \
  {                                                                 \
    const uint4 h4 = *(const uint4*)&hb[16 + 4 * (M)];              \
    ai = dot2(w0_##M##x, h4.x, ai); ai = dot2(w0_##M##y, h4.y, ai); \
    ai = dot2(w0_##M##z, h4.z, ai); ai = dot2(w0_##M##w, h4.w, ai); \
    af = dot2(w1_##M##x, h4.x, af); af = dot2(w1_##M##y, h4.y, af); \
    af = dot2(w1_##M##z, h4.z, af); af = dot2(w1_##M##w, h4.w, af); \
    ag = dot2(w2_##M##x, h4.x, ag); ag = dot2(w2_##M##y, h4.y, ag); \
    ag = dot2(w2_##M##z, h4.z, ag); ag = dot2(w2_##M##w, h4.w, ag); \
    ao = dot2(w3_##M##x, h4.x, ao); ao = dot2(w3_##M##y, h4.y, ao); \
    ao = dot2(w3_##M##z, h4.z, ao); ao = dot2(w3_##M##w, h4.w, ao); \
  }
      DOTM(0) DOTM(1) DOTM(2) DOTM(3) DOTM(4) DOTM(5) DOTM(6)
      DOTM(7) DOTM(8) DOTM(9) DOTM(10) DOTM(11) DOTM(12) DOTM(13)
      DOTM(14) DOTM(15) DOTM(16) DOTM(17) DOTM(18) DOTM(19) DOTM(20)
      DOTM(21) DOTM(22) DOTM(23) DOTM(24) DOTM(25) DOTM(26) DOTM(27)
#undef DOTM
      // thread-local gate combine + state update
      const float i_ = sigmoid_f(ai + xq.x);
      const float f_ = sigmoid_f(af + xq.y);
      const float g_ = tanh_f(ag + xq.z);
      const float o_ = sigmoid_f(ao + xq.w);
      cst = f_ * cst + i_ * g_;
      hval = o_ * tanh_f(cst);
      ((_Float16*)h2l[(s + 1) & 1])[tid] = (_Float16)hval;
      s++;
      __syncthreads();  // write buffer visible; it is next step's read buffer
    }
    HH[((frame + 1) * 64 + b) * 256 + tid] = hval;
  }
}

// Hl[i][b][p] = HH[i][b]·W_lh[p] + b_lh[p]. One block per frame.
__global__ void k_hl(const float* __restrict__ HH,
                     const unsigned* __restrict__ wlh_h2,
                     const float* __restrict__ blh, float* __restrict__ Hl) {
  const int i = blockIdx.x;
  const int tid = threadIdx.x;  // 256
  __shared__ __align__(16) unsigned Ah[64 * 132];
  __shared__ __align__(16) unsigned Bh[128 * 132];
  for (int idx = tid; idx < 64 * 128; idx += 256) {
    const int r = idx >> 7, kp = idx & 127;
    const float* s = HH + ((size_t)(i * 64 + r)) * 256 + 2 * kp;
    Ah[r * 132 + kp] = pack2(s[0], s[1]);
  }
  for (int idx = tid; idx < 128 * 128; idx += 256) {
    const int o = idx >> 7, kp = idx & 127;
    Bh[o * 132 + kp] = wlh_h2[o * 128 + kp];
  }
  __syncthreads();
  const int ry = tid >> 4, px = tid & 15;
  float acc[4][8];
#pragma unroll
  for (int k = 0; k < 4; k++)
#pragma unroll
    for (int j = 0; j < 8; j++) acc[k][j] = 0.f;
  for (int kb = 0; kb < 32; kb++) {
    uint4 a4[4], b4[8];
#pragma unroll
    for (int k = 0; k < 4; k++) a4[k] = *(const uint4*)&Ah[(16 * k + ry) * 132 + 4 * kb];
#pragma unroll
    for (int j = 0; j < 8; j++) b4[j] = *(const uint4*)&Bh[(16 * j + px) * 132 + 4 * kb];
#pragma unroll
    for (int k = 0; k < 4; k++)
#pragma unroll
      for (int j = 0; j < 8; j++) {
        acc[k][j] = dot2(a4[k].x, b4[j].x, acc[k][j]);
        acc[k][j] = dot2(a4[k].y, b4[j].y, acc[k][j]);
        acc[k][j] = dot2(a4[k].z, b4[j].z, acc[k][j]);
        acc[k][j] = dot2(a4[k].w, b4[j].w, acc[k][j]);
      }
  }
#pragma unroll
  for (int k = 0; k < 4; k++)
#pragma unroll
    for (int j = 0; j < 8; j++)
      Hl[(i * 64 + 16 * k + ry) * 128 + 16 * j + px] = acc[k][j] + blh[16 * j + px];
}

// Fused Vp GEMM + z. Rows = flattened (b,g) within frame i (2304 rows, tiles
// of 128). z[b,g] = sum_p w[p]*tanh(Hl[b,p] + Vp[b,g,p]).
__global__ void k_att_z(const float* __restrict__ cnn,
                        const unsigned* __restrict__ wcn_h2,
                        const float* __restrict__ bcn,
                        const float* __restrict__ Hl,
                        const float* __restrict__ wwt,
                        float* __restrict__ zbuf) {
  const int bid = blockIdx.x;  // 576 = 32 frames * 18 row tiles
  const int i = bid / 18, rt = bid - 18 * i;
  const int tid = threadIdx.x;  // 256
  const int r0 = rt * 128;
  __shared__ __align__(16) unsigned As[128 * 132];
  __shared__ __align__(16) unsigned Bs[128 * 132];
  __shared__ float zpart[128 * 16];
  __shared__ float Hls[5 * 128];
  __shared__ float wws[128];
  __shared__ float bcs[128];

  for (int idx = tid; idx < 128 * 128; idx += 256) {
    const int r = idx >> 7, kp = idx & 127;
    const int R = r0 + r;
    const int b = R / 36, g = R - b * 36;
    const float* src = cnn + (((size_t)b * 32 + i) * 36 + g) * 256 + 2 * kp;
    As[r * 132 + kp] = pack2(src[0], src[1]);
  }
  for (int idx = tid; idx < 128 * 128; idx += 256) {
    const int o = idx >> 7, kp = idx & 127;
    Bs[o * 132 + kp] = wcn_h2[o * 128 + kp];
  }
  const int bmin = r0 / 36;
  for (int idx = tid; idx < 5 * 128; idx += 256) {
    const int bb = bmin + (idx >> 7);
    if (bb < 64) Hls[idx] = Hl[(i * 64 + bb) * 128 + (idx & 127)];
  }
  if (tid < 128) {
    wws[tid] = wwt[tid];
    bcs[tid] = bcn[tid];
  }
  __syncthreads();

  const int ry = tid >> 4, px = tid & 15;
  float acc[8][8];
#pragma unroll
  for (int k = 0; k < 8; k++)
#pragma unroll
    for (int j = 0; j < 8; j++) acc[k][j] = bcs[16 * j + px];
  for (int kb = 0; kb < 32; kb++) {
    uint4 a4[8], b4[8];
#pragma unroll
    for (int k = 0; k < 8; k++) a4[k] = *(const uint4*)&As[(16 * k + ry) * 132 + 4 * kb];
#pragma unroll
    for (int j = 0; j < 8; j++) b4[j] = *(const uint4*)&Bs[(16 * j + px) * 132 + 4 * kb];
#pragma unroll
    for (int k = 0; k < 8; k++)
#pragma unroll
      for (int j = 0; j < 8; j++) {
        acc[k][j] = dot2(a4[k].x, b4[j].x, acc[k][j]);
        acc[k][j] = dot2(a4[k].y, b4[j].y, acc[k][j]);
        acc[k][j] = dot2(a4[k].z, b4[j].z, acc[k][j]);
        acc[k][j] = dot2(a4[k].w, b4[j].w, acc[k][j]);
      }
  }
#pragma unroll
  for (int k = 0; k < 8; k++) {
    const int r = 16 * k + ry;
    const int R = r0 + r;
    const int b = R / 36;
    const float* HlRow = &Hls[(b - bmin) * 128];
    float zp = 0.f;
#pragma unroll
    for (int j = 0; j < 8; j++) {
      const int po = 16 * j + px;
      zp += wws[po] * tanh_f(HlRow[po] + acc[k][j]);
    }
    zpart[r * 16 + px] = zp;
  }
  __syncthreads();
  if (tid < 128) {
    float z = 0.f;
#pragma unroll
    for (int x = 0; x < 16; x++) z += zpart[tid * 16 + x];
    const int R = r0 + tid;
    const int b = R / 36, g = R - b * 36;
    zbuf[(i * 64 + b) * 36 + g] = z;
  }
}

// Scrambled softmax + weighted V sum; builds fc = [spatial_feat | h_next].
__global__ void k_att_sf(const float* __restrict__ cnn,
                         const float* __restrict__ zbuf,
                         const float* __restrict__ HH,
                         float* __restrict__ fc) {
  const int bid = blockIdx.x;  // 2048 = i*64 + b
  const int i = bid >> 6, b = bid & 63;
  const int tid = threadIdx.x;  // 256
  __shared__ float zl[36];
  __shared__ float el[40];
  __shared__ float red[1];
  if (tid < 36) {
    const int idx = b * 36 + tid;  // scramble: z.T.reshape(64,36)
    zl[tid] = zbuf[(i * 64 + (idx & 63)) * 36 + (idx >> 6)];
  }
  __syncthreads();
  if (tid == 0) {
    float m = zl[0];
    for (int g = 1; g < 36; g++) m = fmaxf(m, zl[g]);
    float s = 0.f;
    for (int g = 0; g < 36; g++) {
      const float e = __expf(zl[g] - m);
      el[g] = e;
      s += e;
    }
    red[0] = 1.f / s;
  }
  __syncthreads();
  const float inv = red[0];
  float accv = 0.f;
  const float* Vb = cnn + (((size_t)b * 32 + i) * 36) * 256 + tid;
#pragma unroll 4
  for (int g = 0; g < 36; g++) accv += el[g] * Vb[g * 256];
  fc[(size_t)bid * 512 + tid] = accv * inv;
  fc[(size_t)bid * 512 + 256 + tid] = HH[((i + 1) * 64 + b) * 256 + tid];
}

// MLP layers 1/2: (2048,512)@(512,512)+b, output packed f16 pairs.
template <int SRCMODE>  // 0: f32 src (fc), 1: packed-h2 src
__global__ void k_mlp(const void* __restrict__ src,
                      const unsigned* __restrict__ wh2,
                      const float* __restrict__ bias,
                      unsigned* __restrict__ dst) {
  const int bid = blockIdx.x;  // 128 = 32 n-tiles * 4 o-tiles
  const int nb = bid >> 2, ob = bid & 3;
  const int n0 = nb * 64, o0 = ob * 128;
  const int tid = threadIdx.x;
  __shared__ __align__(16) unsigned As[64 * 132];
  __shared__ __align__(16) unsigned Bs[128 * 132];
  const int ry = tid >> 4, px = tid & 15;
  float acc[4][8];
#pragma unroll
  for (int k = 0; k < 4; k++)
#pragma unroll
    for (int m = 0; m < 8; m++)
      acc[k][m] = bias[o0 + 32 * (m >> 1) + 2 * px + (m & 1)];
  for (int kc = 0; kc < 2; kc++) {
    __syncthreads();
    for (int idx = tid; idx < 64 * 128; idx += 256) {
      const int r = idx >> 7, kp = idx & 127;
      if (SRCMODE == 0) {
        const float* s = (const float*)src + ((size_t)(n0 + r)) * 512 + kc * 256 + 2 * kp;
        As[r * 132 + kp] = pack2(s[0], s[1]);
      } else {
        As[r * 132 + kp] = ((const unsigned*)src)[((size_t)(n0 + r)) * 256 + kc * 128 + kp];
      }
    }
    for (int idx = tid; idx < 128 * 128; idx += 256) {
      const int o = idx >> 7, kp = idx & 127;
      Bs[o * 132 + kp] = wh2[((size_t)(o0 + o)) * 256 + kc * 128 + kp];
    }
    __syncthreads();
    for (int kb = 0; kb < 32; kb++) {
      uint4 a4[4], b4[8];
#pragma unroll
      for (int k = 0; k < 4; k++)
        a4[k] = *(const uint4*)&As[(16 * k + ry) * 132 + 4 * kb];
#pragma unroll
      for (int m = 0; m < 8; m++)
        b4[m] = *(const uint4*)&Bs[(32 * (m >> 1) + 2 * px + (m & 1)) * 132 + 4 * kb];
#pragma unroll
      for (int k = 0; k < 4; k++)
#pragma unroll
        for (int m = 0; m < 8; m++) {
          acc[k][m] = dot2(a4[k].x, b4[m].x, acc[k][m]);
          acc[k][m] = dot2(a4[k].y, b4[m].y, acc[k][m]);
          acc[k][m] = dot2(a4[k].z, b4[m].z, acc[k][m]);
          acc[k][m] = dot2(a4[k].w, b4[m].w, acc[k][m]);
        }
    }
  }
#pragma unroll
  for (int k = 0; k < 4; k++) {
    const int n = n0 + 16 * k + ry;
#pragma unroll
    for (int j = 0; j < 4; j++)
      dst[(size_t)n * 256 + (o0 >> 1) + 16 * j + px] =
          pack2(acc[k][2 * j], acc[k][2 * j + 1]);
  }
}

// Final layer: (2048,512) -> 6 classes.
__global__ void k_mlp3(const unsigned* __restrict__ y2h2,
                       const unsigned* __restrict__ wm3h2,
                       const float* __restrict__ bm3,
                       float* __restrict__ out) {
  const int nb = blockIdx.x;  // 32
  const int tid = threadIdx.x;
  __shared__ __align__(16) unsigned Ys[64 * 256];
  __shared__ __align__(16) unsigned Ws[6 * 256];
  for (int idx = tid; idx < 64 * 256; idx += 256)
    Ys[idx] = y2h2[(size_t)nb * 64 * 256 + idx];
  for (int idx = tid; idx < 6 * 256; idx += 256) Ws[idx] = wm3h2[idx];
  __syncthreads();
  for (int u = 0; u < 2; u++) {
    const int idx = tid + u * 256;
    if (idx < 384) {
      const int nl = idx / 6, c = idx - 6 * nl;
      float a0 = 0.f, a1 = 0.f;
#pragma unroll
      for (int kq = 0; kq < 64; kq++) {
        const uint4 y4 = *(const uint4*)&Ys[nl * 256 + 4 * kq];
        const uint4 w4 = *(const uint4*)&Ws[c * 256 + 4 * kq];
        a0 = dot2(y4.x, w4.x, a0);
        a1 = dot2(y4.y, w4.y, a1);
        a0 = dot2(y4.z, w4.z, a0);
        a1 = dot2(y4.w, w4.w, a1);
      }
      out[(size_t)(nb * 64 + nl) * 6 + c] = a0 + a1 + bm3[c];
    }
  }
}

// ---------------------------------------------------------------------------
extern "C" void kernel_launch(void* const* d_in, const int* in_sizes, int n_in,
                              void* d_out, int out_size, void* d_ws,
                              size_t ws_size, hipStream_t stream) {
  (void)in_sizes; (void)n_in; (void)out_size; (void)ws_size;
  const float* cnn  = (const float*)d_in[0];
  const float* gaze = (const float*)d_in[1];
  const float* W_lh = (const float*)d_in[2];
  const float* b_lh = (const float*)d_in[3];
  const float* W_cn = (const float*)d_in[4];
  const float* b_cn = (const float*)d_in[5];
  const float* w_wt = (const float*)d_in[6];
  const float* Wih  = (const float*)d_in[7];
  const float* Whh  = (const float*)d_in[8];
  const float* bih  = (const float*)d_in[9];
  const float* bhh  = (const float*)d_in[10];
  const float* Wh1  = (const float*)d_in[11];
  const float* bh1  = (const float*)d_in[12];
  const float* Wh2  = (const float*)d_in[13];
  const float* bh2  = (const float*)d_in[14];
  const float* Wc1  = (const float*)d_in[15];
  const float* bc1  = (const float*)d_in[16];
  const float* Wc2  = (const float*)d_in[17];
  const float* bc2  = (const float*)d_in[18];
  const float* Wm1  = (const float*)d_in[19];
  const float* bm1  = (const float*)d_in[20];
  const float* Wm2  = (const float*)d_in[21];
  const float* bm2  = (const float*)d_in[22];
  const float* Wm3  = (const float*)d_in[23];
  const float* bm3  = (const float*)d_in[24];
  float* out = (float*)d_out;

  unsigned* W = (unsigned*)d_ws;
  float* Wf = (float*)d_ws;
  // workspace offsets in dwords
  const size_t O_xg  = 0;                    // [31][64][256][4] f32
  const size_t O_wv  = 2031616;              // [28][1024] uint4 = 114688 u32
  const size_t O_wl  = O_wv + 114688;        // [1024][16]     u32
  const size_t O_HH  = O_wl + 16384;         // [33][64][256]  f32
  const size_t O_c0  = O_HH + 540672;        // [64][256]      f32
  const size_t O_Hl  = O_c0 + 16384;         // [32][64][128]  f32
  const size_t O_z   = O_Hl + 262144;        // [32][64][36]   f32
  const size_t O_fc  = O_z + 73728;          // [2048][512]    f32
  const size_t O_y1  = O_fc + 1048576;       // [2048][256]    u32 (h2)
  const size_t O_y2  = O_y1 + 524288;        // [2048][256]    u32 (h2)
  const size_t O_wcn = O_y2 + 524288;        // [128][128]     u32
  const size_t O_wlh = O_wcn + 16384;
  const size_t O_wm1 = O_wlh + 16384;        // [512][256]
  const size_t O_wm2 = O_wm1 + 131072;
  const size_t O_wm3 = O_wm2 + 131072;       // [6][256]

  float* xg  = Wf + O_xg;
  float* HH  = Wf + O_HH;
  float* c0f = Wf + O_c0;
  float* Hlf = Wf + O_Hl;
  float* zf  = Wf + O_z;
  float* fcf = Wf + O_fc;

  // --- prepacking (independent) ---
  k_pack_wv<<<512, 256, 0, stream>>>(Whh, W + O_wv, W + O_wl);
  k_packh2<<<64, 256, 0, stream>>>(W_cn, W + O_wcn, 16384);
  k_packh2<<<64, 256, 0, stream>>>(W_lh, W + O_wlh, 16384);
  k_packh2<<<512, 256, 0, stream>>>(Wm1, W + O_wm1, 131072);
  k_packh2<<<512, 256, 0, stream>>>(Wm2, W + O_wm2, 131072);
  k_packh2<<<6, 256, 0, stream>>>(Wm3, W + O_wm3, 1536);
  k_xg<<<7936, 256, 0, stream>>>(gaze, Wih, bih, bhh, xg);
  k_init<<<64, 256, 0, stream>>>(gaze, Wh1, bh1, Wh2, bh2, Wc1, bc1, Wc2, bc2,
                                 HH, c0f);
  // --- the sequential chain ---
  k_lstm<<<64, 256, 0, stream>>>(xg, W + O_wv, W + O_wl, c0f, HH);
  // --- batched attention ---
  k_hl<<<32, 256, 0, stream>>>(HH, W + O_wlh, b_lh, Hlf);
  k_att_z<<<576, 256, 0, stream>>>(cnn, W + O_wcn, b_cn, Hlf, w_wt, zf);
  k_att_sf<<<2048, 256, 0, stream>>>(cnn, zf, HH, fcf);
  // --- batched MLP ---
  k_mlp<0><<<128, 256, 0, stream>>>((const void*)fcf, W + O_wm1, bm1, W + O_y1);
  k_mlp<1><<<128, 256, 0, stream>>>((const void*)(W + O_y1), W + O_wm2, bm2, W + O_y2);
  k_mlp3<<<32, 256, 0, stream>>>(W + O_y2, W + O_wm3, bm3, out);
}

// Round 10
// 1963.592 us; speedup vs baseline: 9.0028x; 1.0128x over previous
//
#include <hip/hip_runtime.h>
#include <math.h>

// ---------------------------------------------------------------------------
// SpatialAttentionModel on MI355X.
// R10: k_lstm redesigned for the REAL register budget discovered in R4-R9
// (RA grants 2048/waves targeting 2 blocks/CU: 256thr -> 256 VGPRs; pins only
// hold if total live <= budget). 256 threads, thread owns 4 gate rows:
//   pairs 88..127 x4 rows = 160 dwords pinned VGPR (fits: ~230 total live)
//   pairs  0..31  all rows = 128KB static LDS (stride-36, 0-conflict proven)
//   pairs 32..87  x4 rows = 229KB/step streamed via 8-slot register ring
// One barrier/step (double-buffered h). Streams / LDS / VALU overlap on
// separate pipes -> ~1us/step predicted.
// Plus: Vp GEMM (LSTM-independent) + wm/wlh packs fused into the same launch
// as extra blocks -> run on the 192 idle CUs under the LSTM window.
// ws_size runtime guard falls back to the old fused k_att_z path.
// ---------------------------------------------------------------------------

typedef _Float16 h2_t __attribute__((ext_vector_type(2)));

#if __has_builtin(__builtin_amdgcn_fdot2)
#define HAVE_FDOT2 1
#else
#define HAVE_FDOT2 0
#endif

__device__ __forceinline__ float dot2(unsigned w, unsigned h, float acc) {
#if HAVE_FDOT2
  return __builtin_amdgcn_fdot2(__builtin_bit_cast(h2_t, w),
                                __builtin_bit_cast(h2_t, h), acc, false);
#else
  h2_t a = __builtin_bit_cast(h2_t, w);
  h2_t b = __builtin_bit_cast(h2_t, h);
  return acc + (float)a[0] * (float)b[0] + (float)a[1] * (float)b[1];
#endif
}

__device__ __forceinline__ unsigned pack2(float a, float b) {
  h2_t p;
  p[0] = (_Float16)a;
  p[1] = (_Float16)b;
  return __builtin_bit_cast(unsigned, p);
}

__device__ __forceinline__ float sigmoid_f(float x) {
  return __builtin_amdgcn_rcpf(1.f + __expf(-x));
}
__device__ __forceinline__ float tanh_f(float x) {
  return 1.f - 2.f * __builtin_amdgcn_rcpf(1.f + __expf(2.f * x));
}

// ---------------------------------------------------------------------------
// Pack Whh into the three LSTM tiers.
//  wlds_pack[row*32+p], p<32  : pairs 0..31 (static LDS tier)
//  wst  u32[56*1024]: quad j<56 (M=j>>2, G=j&3): pairs 32+4M..35+4M of row
//        G*256+t, laid out [j][t][4] dwords.
//  wvp  u32[40*1024]: quad k<40 (G=k/10, Q=k%10): pairs 88+4Q..91+4Q of row
//        G*256+t, laid out [k][t][4].
__global__ void k_pack_lstm(const float* __restrict__ Whh,
                            unsigned* __restrict__ wlds_pack,
                            unsigned* __restrict__ wst,
                            unsigned* __restrict__ wvp) {
  const int idx = blockIdx.x * 256 + threadIdx.x;  // < 131072
  if (idx < 32768) {
    const int row = idx >> 5, pair = idx & 31;
    wlds_pack[idx] =
        pack2(Whh[row * 256 + 2 * pair], Whh[row * 256 + 2 * pair + 1]);
  } else if (idx < 90112) {
    const int rel = idx - 32768;
    const int j = rel >> 10, t = (rel >> 2) & 255, d = rel & 3;
    const int row = (j & 3) * 256 + t;
    const int pair = 32 + 4 * (j >> 2) + d;
    wst[rel] = pack2(Whh[row * 256 + 2 * pair], Whh[row * 256 + 2 * pair + 1]);
  } else {
    const int rel = idx - 90112;
    const int k = rel >> 10, t = (rel >> 2) & 255, d = rel & 3;
    const int G = k / 10, Q = k - 10 * G;
    const int row = G * 256 + t;
    const int pair = 88 + 4 * Q + d;
    wvp[rel] = pack2(Whh[row * 256 + 2 * pair], Whh[row * 256 + 2 * pair + 1]);
  }
}

// Generic f32 -> packed-f16-pair converter.
__global__ void k_packh2(const float* __restrict__ src,
                         unsigned* __restrict__ dst, int n) {
  const int i = blockIdx.x * 256 + threadIdx.x;
  if (i < n) dst[i] = pack2(src[2 * i], src[2 * i + 1]);
}

// xg4[t][b][r][q] = gaze[b,t,:]·Wih[q*256+r,:] + bih + bhh (gate-minor f4).
__global__ void k_xg(const float* __restrict__ gaze,
                     const float* __restrict__ Wih,
                     const float* __restrict__ bih,
                     const float* __restrict__ bhh,
                     float* __restrict__ xg4) {
  const int idx = blockIdx.x * 256 + threadIdx.x;
  if (idx >= 31 * 64 * 1024) return;
  const int q = idx & 3;
  const int r = (idx >> 2) & 255;
  const int b = (idx >> 10) & 63;
  const int t = idx >> 16;
  const int j = q * 256 + r;
  const float* gz = gaze + (b * 32 + t) * 3;
  xg4[idx] = gz[0] * Wih[j * 3 + 0] + gz[1] * Wih[j * 3 + 1] +
             gz[2] * Wih[j * 3 + 2] + bih[j] + bhh[j];
}

// h0/c0 init.
__global__ void k_init(const float* __restrict__ gaze,
                       const float* __restrict__ Wh1, const float* __restrict__ bh1,
                       const float* __restrict__ Wh2, const float* __restrict__ bh2,
                       const float* __restrict__ Wc1, const float* __restrict__ bc1,
                       const float* __restrict__ Wc2, const float* __restrict__ bc2,
                       float* __restrict__ HH, float* __restrict__ c0) {
  const int b = blockIdx.x;
  const int tid = threadIdx.x;  // 256
  __shared__ float mg[3];
  __shared__ float t1h[256], t1c[256];
  if (tid < 3) {
    float s = 0.f;
    for (int t = 0; t < 32; t++) s += gaze[(b * 32 + t) * 3 + tid];
    mg[tid] = s * (1.f / 32.f);
  }
  __syncthreads();
  {
    float a = mg[0] * Wh1[tid * 3 + 0] + mg[1] * Wh1[tid * 3 + 1] +
              mg[2] * Wh1[tid * 3 + 2] + bh1[tid];
    t1h[tid] = tanhf(a);
    float c = mg[0] * Wc1[tid * 3 + 0] + mg[1] * Wc1[tid * 3 + 1] +
              mg[2] * Wc1[tid * 3 + 2] + bc1[tid];
    t1c[tid] = tanhf(c);
  }
  __syncthreads();
  float s1 = bh2[tid], s2 = bc2[tid];
  for (int k = 0; k < 256; k++) {
    s1 += t1h[k] * Wh2[tid * 256 + k];
    s2 += t1c[k] * Wc2[tid * 256 + k];
  }
  HH[b * 256 + tid] = tanhf(tanhf(s1));
  c0[b * 256 + tid] = tanhf(tanhf(s2));
}

// ---------------------------------------------------------------------------
// Fused kernel: blocks [0,64) = LSTM chains; [64,64+nvp) = Vp GEMM;
// [64+nvp, 64+nvp+17) = weight packs for the MLP/hl stage.
__global__ __launch_bounds__(256) void k_fused(
    const float* __restrict__ xg4, const unsigned* __restrict__ wst,
    const unsigned* __restrict__ wvp, const unsigned* __restrict__ wlds_pack,
    const float* __restrict__ c0, float* __restrict__ HH,
    const float* __restrict__ cnn, const unsigned* __restrict__ wcn_h2,
    const float* __restrict__ bcn, unsigned* __restrict__ Vp, int nvp,
    const float* __restrict__ Wm1, unsigned* __restrict__ wm1d,
    const float* __restrict__ Wm2, unsigned* __restrict__ wm2d,
    const float* __restrict__ Wm3, unsigned* __restrict__ wm3d,
    const float* __restrict__ Wlh, unsigned* __restrict__ wlhd) {
  const int bid = blockIdx.x;
  const int tid = threadIdx.x;
  __shared__ __align__(16) unsigned smem[37120];  // 148480 B

  if (bid < 64) {
    // ================= LSTM path =================
    const int b = bid;
    unsigned* wlds = smem;  // [1024*36]
    unsigned(*h2l)[128] = reinterpret_cast<unsigned(*)[128]>(smem + 36864);

    for (int i = tid; i < 32768; i += 256)
      wlds[(i >> 5) * 36 + (i & 31)] = wlds_pack[i];

    // 40 pinned quads = 160 persistent dwords: vG_Q = pairs 88+4Q.. of row
    // G*256+tid.
    const uint4* wvq = (const uint4*)wvp + tid;
#define DECLV(G, Q)                                                       \
  const uint4 t##G##_##Q = wvq[((G)*10 + (Q)) * 256];                     \
  unsigned v##G##_##Q##x = t##G##_##Q.x, v##G##_##Q##y = t##G##_##Q.y,    \
           v##G##_##Q##z = t##G##_##Q.z, v##G##_##Q##w = t##G##_##Q.w;
#define P4(G, Q)                                                          \
  "+v"(v##G##_##Q##x), "+v"(v##G##_##Q##y), "+v"(v##G##_##Q##z),          \
      "+v"(v##G##_##Q##w)
    DECLV(0, 0) DECLV(0, 1) DECLV(0, 2) DECLV(0, 3) DECLV(0, 4)
    asm volatile("" : P4(0, 0), P4(0, 1), P4(0, 2), P4(0, 3), P4(0, 4));
    DECLV(0, 5) DECLV(0, 6) DECLV(0, 7) DECLV(0, 8) DECLV(0, 9)
    asm volatile("" : P4(0, 5), P4(0, 6), P4(0, 7), P4(0, 8), P4(0, 9));
    DECLV(1, 0) DECLV(1, 1) DECLV(1, 2) DECLV(1, 3) DECLV(1, 4)
    asm volatile("" : P4(1, 0), P4(1, 1), P4(1, 2), P4(1, 3), P4(1, 4));
    DECLV(1, 5) DECLV(1, 6) DECLV(1, 7) DECLV(1, 8) DECLV(1, 9)
    asm volatile("" : P4(1, 5), P4(1, 6), P4(1, 7), P4(1, 8), P4(1, 9));
    DECLV(2, 0) DECLV(2, 1) DECLV(2, 2) DECLV(2, 3) DECLV(2, 4)
    asm volatile("" : P4(2, 0), P4(2, 1), P4(2, 2), P4(2, 3), P4(2, 4));
    DECLV(2, 5) DECLV(2, 6) DECLV(2, 7) DECLV(2, 8) DECLV(2, 9)
    asm volatile("" : P4(2, 5), P4(2, 6), P4(2, 7), P4(2, 8), P4(2, 9));
    DECLV(3, 0) DECLV(3, 1) DECLV(3, 2) DECLV(3, 3) DECLV(3, 4)
    asm volatile("" : P4(3, 0), P4(3, 1), P4(3, 2), P4(3, 3), P4(3, 4));
    DECLV(3, 5) DECLV(3, 6) DECLV(3, 7) DECLV(3, 8) DECLV(3, 9)
    asm volatile("" : P4(3, 5), P4(3, 6), P4(3, 7), P4(3, 8), P4(3, 9));
#undef P4
#undef DECLV

    float cst = c0[b * 256 + tid];
    ((_Float16*)h2l[0])[tid] = (_Float16)HH[b * 256 + tid];
    __syncthreads();

    const uint4* wstp = (const uint4*)wst + tid;
    int s = 0;
    float hval = 0.f;

    for (int frame = 0; frame < 32; frame++) {
      const int L = frame ? frame : 1;
      for (int t = 0; t < L; t++) {
        // stream ring prologue: quads j=0..7 in flight
        uint4 q0 = wstp[0 * 256], q1 = wstp[1 * 256], q2 = wstp[2 * 256],
              q3 = wstp[3 * 256], q4 = wstp[4 * 256], q5 = wstp[5 * 256],
              q6 = wstp[6 * 256], q7 = wstp[7 * 256];
        const float4 xq =
            *(const float4*)&xg4[(((size_t)t * 64 + b) * 256 + tid) * 4];
        const unsigned* hb = h2l[s & 1];
        float ai = 0.f, af = 0.f, ag = 0.f, ao = 0.f;

        // ---- static LDS tier: pairs 0..31 (h quads 0..7) ----
#define SP(pq)                                                             \
  {                                                                        \
    const uint4 hq = *(const uint4*)&hb[4 * (pq)];                         \
    const uint4 a0 = *(const uint4*)&wlds[tid * 36 + 4 * (pq)];            \
    const uint4 a1 = *(const uint4*)&wlds[(tid + 256) * 36 + 4 * (pq)];    \
    const uint4 a2 = *(const uint4*)&wlds[(tid + 512) * 36 + 4 * (pq)];    \
    const uint4 a3 = *(const uint4*)&wlds[(tid + 768) * 36 + 4 * (pq)];    \
    ai = dot2(a0.x, hq.x, ai); ai = dot2(a0.y, hq.y, ai);                  \
    ai = dot2(a0.z, hq.z, ai); ai = dot2(a0.w, hq.w, ai);                  \
    af = dot2(a1.x, hq.x, af); af = dot2(a1.y, hq.y, af);                  \
    af = dot2(a1.z, hq.z, af); af = dot2(a1.w, hq.w, af);                  \
    ag = dot2(a2.x, hq.x, ag); ag = dot2(a2.y, hq.y, ag);                  \
    ag = dot2(a2.z, hq.z, ag); ag = dot2(a2.w, hq.w, ag);                  \
    ao = dot2(a3.x, hq.x, ao); ao = dot2(a3.y, hq.y, ao);                  \
    ao = dot2(a3.z, hq.z, ao); ao = dot2(a3.w, hq.w, ao);                  \
  }
        SP(0) SP(1) SP(2) SP(3) SP(4) SP(5) SP(6) SP(7)
#undef SP

        // ---- streamed tier: pairs 32..87 (h quads 8..21), 8-slot ring ----
#define STRG(M, A0, A1, A2, A3)                                            \
  {                                                                        \
    const uint4 hq = *(const uint4*)&hb[4 * (8 + (M))];                    \
    ai = dot2(q##A0.x, hq.x, ai); ai = dot2(q##A0.y, hq.y, ai);            \
    ai = dot2(q##A0.z, hq.z, ai); ai = dot2(q##A0.w, hq.w, ai);            \
    if (4 * (M) + 8 < 56) q##A0 = wstp[(4 * (M) + 8) * 256];               \
    af = dot2(q##A1.x, hq.x, af); af = dot2(q##A1.y, hq.y, af);            \
    af = dot2(q##A1.z, hq.z, af); af = dot2(q##A1.w, hq.w, af);            \
    if (4 * (M) + 9 < 56) q##A1 = wstp[(4 * (M) + 9) * 256];               \
    ag = dot2(q##A2.x, hq.x, ag); ag = dot2(q##A2.y, hq.y, ag);            \
    ag = dot2(q##A2.z, hq.z, ag); ag = dot2(q##A2.w, hq.w, ag);            \
    if (4 * (M) + 10 < 56) q##A2 = wstp[(4 * (M) + 10) * 256];             \
    ao = dot2(q##A3.x, hq.x, ao); ao = dot2(q##A3.y, hq.y, ao);            \
    ao = dot2(q##A3.z, hq.z, ao); ao = dot2(q##A3.w, hq.w, ao);            \
    if (4 * (M) + 11 < 56) q##A3 = wstp[(4 * (M) + 11) * 256];             \
  }
        STRG(0, 0, 1, 2, 3) STRG(1, 4, 5, 6, 7)
        STRG(2, 0, 1, 2, 3) STRG(3, 4, 5, 6, 7)
        STRG(4, 0, 1, 2, 3) STRG(5, 4, 5, 6, 7)
        STRG(6, 0, 1, 2, 3) STRG(7, 4, 5, 6, 7)
        STRG(8, 0, 1, 2, 3) STRG(9, 4, 5, 6, 7)
        STRG(10, 0, 1, 2, 3) STRG(11, 4, 5, 6, 7)
        STRG(12, 0, 1, 2, 3) STRG(13, 4, 5, 6, 7)
#undef STRG

        // ---- pinned tier: pairs 88..127 (h quads 22..31) ----
#define VSTEP(Q)                                                           \
  {                                                                        \
    const uint4 hq = *(const uint4*)&hb[4 * (22 + (Q))];                   \
    ai = dot2(v0_##Q##x, hq.x, ai); ai = dot2(v0_##Q##y, hq.y, ai);        \
    ai = dot2(v0_##Q##z, hq.z, ai); ai = dot2(v0_##Q##w, hq.w, ai);        \
    af = dot2(v1_##Q##x, hq.x, af); af = dot2(v1_##Q##y, hq.y, af);        \
    af = dot2(v1_##Q##z, hq.z, af); af = dot2(v1_##Q##w, hq.w, af);        \
    ag = dot2(v2_##Q##x, hq.x, ag); ag = dot2(v2_##Q##y, hq.y, ag);        \
    ag = dot2(v2_##Q##z, hq.z, ag); ag = dot2(v2_##Q##w, hq.w, ag);        \
    ao = dot2(v3_##Q##x, hq.x, ao); ao = dot2(v3_##Q##y, hq.y, ao);        \
    ao = dot2(v3_##Q##z, hq.z, ao); ao = dot2(v3_##Q##w, hq.w, ao);        \
  }
        VSTEP(0) VSTEP(1) VSTEP(2) VSTEP(3) VSTEP(4)
        VSTEP(5) VSTEP(6) VSTEP(7) VSTEP(8) VSTEP(9)
#undef VSTEP

        const float i_ = sigmoid_f(ai + xq.x);
        const float f_ = sigmoid_f(af + xq.y);
        const float g_ = tanh_f(ag + xq.z);
        const float o_ = sigmoid_f(ao + xq.w);
        cst = f_ * cst + i_ * g_;
        hval = o_ * tanh_f(cst);
        ((_Float16*)h2l[(s + 1) & 1])[tid] = (_Float16)hval;
        s++;
        __syncthreads();
      }
      HH[((frame + 1) * 64 + b) * 256 + tid] = hval;
    }
  } else if (bid < 64 + nvp) {
    // ================= Vp GEMM path =================
    const int vb = bid - 64;  // < 576
    const int i = vb / 18, rt = vb - 18 * i;
    const int r0 = rt * 128;
    unsigned* As = smem;          // 128*132
    unsigned* Bs = smem + 16896;  // 128*132
    float* bcs = (float*)(smem + 33792);  // 128

    for (int idx = tid; idx < 128 * 128; idx += 256) {
      const int r = idx >> 7, kp = idx & 127;
      const int R = r0 + r;
      const int b = R / 36, g = R - b * 36;
      const float* src = cnn + (((size_t)b * 32 + i) * 36 + g) * 256 + 2 * kp;
      As[r * 132 + kp] = pack2(src[0], src[1]);
    }
    for (int idx = tid; idx < 128 * 128; idx += 256) {
      const int o = idx >> 7, kp = idx & 127;
      Bs[o * 132 + kp] = wcn_h2[o * 128 + kp];
    }
    if (tid < 128) bcs[tid] = bcn[tid];
    __syncthreads();

    const int ry = tid >> 4, px = tid & 15;
    float acc[8][8];
#pragma unroll
    for (int k = 0; k < 8; k++)
#pragma unroll
      for (int m = 0; m < 8; m++)
        acc[k][m] = bcs[32 * (m >> 1) + 2 * px + (m & 1)];
    for (int kb = 0; kb < 32; kb++) {
      uint4 a4[8], b4[8];
#pragma unroll
      for (int k = 0; k < 8; k++)
        a4[k] = *(const uint4*)&As[(16 * k + ry) * 132 + 4 * kb];
#pragma unroll
      for (int m = 0; m < 8; m++)
        b4[m] = *(const uint4*)&Bs[(32 * (m >> 1) + 2 * px + (m & 1)) * 132 + 4 * kb];
#pragma unroll
      for (int k = 0; k < 8; k++)
#pragma unroll
        for (int m = 0; m < 8; m++) {
          acc[k][m] = dot2(a4[k].x, b4[m].x, acc[k][m]);
          acc[k][m] = dot2(a4[k].y, b4[m].y, acc[k][m]);
          acc[k][m] = dot2(a4[k].z, b4[m].z, acc[k][m]);
          acc[k][m] = dot2(a4[k].w, b4[m].w, acc[k][m]);
        }
    }
#pragma unroll
    for (int k = 0; k < 8; k++) {
      const int R = r0 + 16 * k + ry;
#pragma unroll
      for (int jj = 0; jj < 4; jj++)
        Vp[((size_t)i * 2304 + R) * 64 + 16 * jj + px] =
            pack2(acc[k][2 * jj], acc[k][2 * jj + 1]);
    }
  } else {
    // ================= pack path (17 blocks) =================
    const int pb = bid - 64 - nvp;
    if (pb < 8) {
      const int base = pb * 16384;
      for (int j = tid; j < 16384; j += 256)
        wm1d[base + j] = pack2(Wm1[2 * (base + j)], Wm1[2 * (base + j) + 1]);
    } else if (pb < 16) {
      const int base = (pb - 8) * 16384;
      for (int j = tid; j < 16384; j += 256)
        wm2d[base + j] = pack2(Wm2[2 * (base + j)], Wm2[2 * (base + j) + 1]);
    } else {
      for (int j = tid; j < 1536; j += 256)
        wm3d[j] = pack2(Wm3[2 * j], Wm3[2 * j + 1]);
      for (int j = tid; j < 16384; j += 256)
        wlhd[j] = pack2(Wlh[2 * j], Wlh[2 * j + 1]);
    }
  }
}

// z finish: z[b,g] = sum_p w[p]*tanh(Hl[i,b,p] + Vp[i,R,p]).
__global__ void k_zfin(const unsigned* __restrict__ Vp,
                       const float* __restrict__ Hl,
                       const float* __restrict__ wwt,
                       float* __restrict__ zbuf) {
  const int bid = blockIdx.x;  // 576
  const int i = bid / 18, rt = bid - 18 * i;
  const int r0 = rt * 128;
  const int tid = threadIdx.x;  // 256
  __shared__ float Hls[5 * 128];
  __shared__ float wws[128];
  __shared__ float zpart[128 * 16];
  const int bmin = r0 / 36;
  for (int idx = tid; idx < 5 * 128; idx += 256) {
    const int bb = bmin + (idx >> 7);
    if (bb < 64) Hls[idx] = Hl[(i * 64 + bb) * 128 + (idx & 127)];
  }
  if (tid < 128) wws[tid] = wwt[tid];
  __syncthreads();
  const int ry = tid >> 4, px = tid & 15;
#pragma unroll
  for (int k = 0; k < 8; k++) {
    const int r = 16 * k + ry;
    const int R = r0 + r;
    const int b = R / 36;
    const unsigned* vr = Vp + ((size_t)i * 2304 + R) * 64;
    const float* Hr = &Hls[(b - bmin) * 128];
    float z = 0.f;
#pragma unroll
    for (int jj = 0; jj < 4; jj++) {
      const int pp = 16 * jj + px;
      const h2_t pr = __builtin_bit_cast(h2_t, vr[pp]);
      z += wws[2 * pp] * tanh_f(Hr[2 * pp] + (float)pr[0]);
      z += wws[2 * pp + 1] * tanh_f(Hr[2 * pp + 1] + (float)pr[1]);
    }
    zpart[r * 16 + px] = z;
  }
  __syncthreads();
  if (tid < 128) {
    float z = 0.f;
#pragma unroll
    for (int x = 0; x < 16; x++) z += zpart[tid * 16 + x];
    const int R = r0 + tid;
    const int b = R / 36, g = R - b * 36;
    zbuf[(i * 64 + b) * 36 + g] = z;
  }
}

// Hl[i][b][p] = HH[i][b]·W_lh[p] + b_lh[p].
__global__ void k_hl(const float* __restrict__ HH,
                     const unsigned* __restrict__ wlh_h2,
                     const float* __restrict__ blh, float* __restrict__ Hl) {
  const int i = blockIdx.x;
  const int tid = threadIdx.x;  // 256
  __shared__ __align__(16) unsigned Ah[64 * 132];
  __shared__ __align__(16) unsigned Bh[128 * 132];
  for (int idx = tid; idx < 64 * 128; idx += 256) {
    const int r = idx >> 7, kp = idx & 127;
    const float* s = HH + ((size_t)(i * 64 + r)) * 256 + 2 * kp;
    Ah[r * 132 + kp] = pack2(s[0], s[1]);
  }
  for (int idx = tid; idx < 128 * 128; idx += 256) {
    const int o = idx >> 7, kp = idx & 127;
    Bh[o * 132 + kp] = wlh_h2[o * 128 + kp];
  }
  __syncthreads();
  const int ry = tid >> 4, px = tid & 15;
  float acc[4][8];
#pragma unroll
  for (int k = 0; k < 4; k++)
#pragma unroll
    for (int j = 0; j < 8; j++) acc[k][j] = 0.f;
  for (int kb = 0; kb < 32; kb++) {
    uint4 a4[4], b4[8];
#pragma unroll
    for (int k = 0; k < 4; k++) a4[k] = *(const uint4*)&Ah[(16 * k + ry) * 132 + 4 * kb];
#pragma unroll
    for (int j = 0; j < 8; j++) b4[j] = *(const uint4*)&Bh[(16 * j + px) * 132 + 4 * kb];
#pragma unroll
    for (int k = 0; k < 4; k++)
#pragma unroll
      for (int j = 0; j < 8; j++) {
        acc[k][j] = dot2(a4[k].x, b4[j].x, acc[k][j]);
        acc[k][j] = dot2(a4[k].y, b4[j].y, acc[k][j]);
        acc[k][j] = dot2(a4[k].z, b4[j].z, acc[k][j]);
        acc[k][j] = dot2(a4[k].w, b4[j].w, acc[k][j]);
      }
  }
#pragma unroll
  for (int k = 0; k < 4; k++)
#pragma unroll
    for (int j = 0; j < 8; j++)
      Hl[(i * 64 + 16 * k + ry) * 128 + 16 * j + px] = acc[k][j] + blh[16 * j + px];
}

// Fallback (small ws): fused Vp GEMM + z.
__global__ void k_att_z(const float* __restrict__ cnn,
                        const unsigned* __restrict__ wcn_h2,
                        const float* __restrict__ bcn,
                        const float* __restrict__ Hl,
                        const float* __restrict__ wwt,
                        float* __restrict__ zbuf) {
  const int bid = blockIdx.x;  // 576
  const int i = bid / 18, rt = bid - 18 * i;
  const int tid = threadIdx.x;  // 256
  const int r0 = rt * 128;
  __shared__ __align__(16) unsigned As[128 * 132];
  __shared__ __align__(16) unsigned Bs[128 * 132];
  __shared__ float zpart[128 * 16];
  __shared__ float Hls[5 * 128];
  __shared__ float wws[128];
  __shared__ float bcs[128];

  for (int idx = tid; idx < 128 * 128; idx += 256) {
    const int r = idx >> 7, kp = idx & 127;
    const int R = r0 + r;
    const int b = R / 36, g = R - b * 36;
    const float* src = cnn + (((size_t)b * 32 + i) * 36 + g) * 256 + 2 * kp;
    As[r * 132 + kp] = pack2(src[0], src[1]);
  }
  for (int idx = tid; idx < 128 * 128; idx += 256) {
    const int o = idx >> 7, kp = idx & 127;
    Bs[o * 132 + kp] = wcn_h2[o * 128 + kp];
  }
  const int bmin = r0 / 36;
  for (int idx = tid; idx < 5 * 128; idx += 256) {
    const int bb = bmin + (idx >> 7);
    if (bb < 64) Hls[idx] = Hl[(i * 64 + bb) * 128 + (idx & 127)];
  }
  if (tid < 128) {
    wws[tid] = wwt[tid];
    bcs[tid] = bcn[tid];
  }
  __syncthreads();

  const int ry = tid >> 4, px = tid & 15;
  float acc[8][8];
#pragma unroll
  for (int k = 0; k < 8; k++)
#pragma unroll
    for (int j = 0; j < 8; j++) acc[k][j] = bcs[16 * j + px];
  for (int kb = 0; kb < 32; kb++) {
    uint4 a4[8], b4[8];
#pragma unroll
    for (int k = 0; k < 8; k++) a4[k] = *(const uint4*)&As[(16 * k + ry) * 132 + 4 * kb];
#pragma unroll
    for (int j = 0; j < 8; j++) b4[j] = *(const uint4*)&Bs[(16 * j + px) * 132 + 4 * kb];
#pragma unroll
    for (int k = 0; k < 8; k++)
#pragma unroll
      for (int j = 0; j < 8; j++) {
        acc[k][j] = dot2(a4[k].x, b4[j].x, acc[k][j]);
        acc[k][j] = dot2(a4[k].y, b4[j].y, acc[k][j]);
        acc[k][j] = dot2(a4[k].z, b4[j].z, acc[k][j]);
        acc[k][j] = dot2(a4[k].w, b4[j].w, acc[k][j]);
      }
  }
#pragma unroll
  for (int k = 0; k < 8; k++) {
    const int r = 16 * k + ry;
    const int R = r0 + r;
    const int b = R / 36;
    const float* HlRow = &Hls[(b - bmin) * 128];
    float zp = 0.f;
#pragma unroll
    for (int j = 0; j < 8; j++) {
      const int po = 16 * j + px;
      zp += wws[po] * tanh_f(HlRow[po] + acc[k][j]);
    }
    zpart[r * 16 + px] = zp;
  }
  __syncthreads();
  if (tid < 128) {
    float z = 0.f;
#pragma unroll
    for (int x = 0; x < 16; x++) z += zpart[tid * 16 + x];
    const int R = r0 + tid;
    const int b = R / 36, g = R - b * 36;
    zbuf[(i * 64 + b) * 36 + g] = z;
  }
}

// Scrambled softmax + weighted V sum; builds fc = [spatial_feat | h_next].
__global__ void k_att_sf(const float* __restrict__ cnn,
                         const float* __restrict__ zbuf,
                         const float* __restrict__ HH,
                         float* __restrict__ fc) {
  const int bid = blockIdx.x;  // 2048
  const int i = bid >> 6, b = bid & 63;
  const int tid = threadIdx.x;  // 256
  __shared__ float zl[36];
  __shared__ float el[40];
  __shared__ float red[1];
  if (tid < 36) {
    const int idx = b * 36 + tid;
    zl[tid] = zbuf[(i * 64 + (idx & 63)) * 36 + (idx >> 6)];
  }
  __syncthreads();
  if (tid == 0) {
    float m = zl[0];
    for (int g = 1; g < 36; g++) m = fmaxf(m, zl[g]);
    float s = 0.f;
    for (int g = 0; g < 36; g++) {
      const float e = __expf(zl[g] - m);
      el[g] = e;
      s += e;
    }
    red[0] = 1.f / s;
  }
  __syncthreads();
  const float inv = red[0];
  float accv = 0.f;
  const float* Vb = cnn + (((size_t)b * 32 + i) * 36) * 256 + tid;
#pragma unroll 4
  for (int g = 0; g < 36; g++) accv += el[g] * Vb[g * 256];
  fc[(size_t)bid * 512 + tid] = accv * inv;
  fc[(size_t)bid * 512 + 256 + tid] = HH[((i + 1) * 64 + b) * 256 + tid];
}

// MLP layers 1/2.
template <int SRCMODE>
__global__ void k_mlp(const void* __restrict__ src,
                      const unsigned* __restrict__ wh2,
                      const float* __restrict__ bias,
                      unsigned* __restrict__ dst) {
  const int bid = blockIdx.x;  // 128
  const int nb = bid >> 2, ob = bid & 3;
  const int n0 = nb * 64, o0 = ob * 128;
  const int tid = threadIdx.x;
  __shared__ __align__(16) unsigned As[64 * 132];
  __shared__ __align__(16) unsigned Bs[128 * 132];
  const int ry = tid >> 4, px = tid & 15;
  float acc[4][8];
#pragma unroll
  for (int k = 0; k < 4; k++)
#pragma unroll
    for (int m = 0; m < 8; m++)
      acc[k][m] = bias[o0 + 32 * (m >> 1) + 2 * px + (m & 1)];
  for (int kc = 0; kc < 2; kc++) {
    __syncthreads();
    for (int idx = tid; idx < 64 * 128; idx += 256) {
      const int r = idx >> 7, kp = idx & 127;
      if (SRCMODE == 0) {
        const float* s = (const float*)src + ((size_t)(n0 + r)) * 512 + kc * 256 + 2 * kp;
        As[r * 132 + kp] = pack2(s[0], s[1]);
      } else {
        As[r * 132 + kp] = ((const unsigned*)src)[((size_t)(n0 + r)) * 256 + kc * 128 + kp];
      }
    }
    for (int idx = tid; idx < 128 * 128; idx += 256) {
      const int o = idx >> 7, kp = idx & 127;
      Bs[o * 132 + kp] = wh2[((size_t)(o0 + o)) * 256 + kc * 128 + kp];
    }
    __syncthreads();
    for (int kb = 0; kb < 32; kb++) {
      uint4 a4[4], b4[8];
#pragma unroll
      for (int k = 0; k < 4; k++)
        a4[k] = *(const uint4*)&As[(16 * k + ry) * 132 + 4 * kb];
#pragma unroll
      for (int m = 0; m < 8; m++)
        b4[m] = *(const uint4*)&Bs[(32 * (m >> 1) + 2 * px + (m & 1)) * 132 + 4 * kb];
#pragma unroll
      for (int k = 0; k < 4; k++)
#pragma unroll
        for (int m = 0; m < 8; m++) {
          acc[k][m] = dot2(a4[k].x, b4[m].x, acc[k][m]);
          acc[k][m] = dot2(a4[k].y, b4[m].y, acc[k][m]);
          acc[k][m] = dot2(a4[k].z, b4[m].z, acc[k][m]);
          acc[k][m] = dot2(a4[k].w, b4[m].w, acc[k][m]);
        }
    }
  }
#pragma unroll
  for (int k = 0; k < 4; k++) {
    const int n = n0 + 16 * k + ry;
#pragma unroll
    for (int j = 0; j < 4; j++)
      dst[(size_t)n * 256 + (o0 >> 1) + 16 * j + px] =
          pack2(acc[k][2 * j], acc[k][2 * j + 1]);
  }
}

// Final layer: (2048,512) -> 6 classes.
__global__ void k_mlp3(const unsigned* __restrict__ y2h2,
                       const unsigned* __restrict__ wm3h2,
                       const float* __restrict__ bm3,
                       float* __restrict__ out) {
  const int nb = blockIdx.x;  // 32
  const int tid = threadIdx.x;
  __shared__ __align__(16) unsigned Ys[64 * 256];
  __shared__ __align__(16) unsigned Ws[6 * 256];
  for (int idx = tid; idx < 64 * 256; idx += 256)
    Ys[idx] = y2h2[(size_t)nb * 64 * 256 + idx];
  for (int idx = tid; idx < 6 * 256; idx += 256) Ws[idx] = wm3h2[idx];
  __syncthreads();
  for (int u = 0; u < 2; u++) {
    const int idx = tid + u * 256;
    if (idx < 384) {
      const int nl = idx / 6, c = idx - 6 * nl;
      float a0 = 0.f, a1 = 0.f;
#pragma unroll
      for (int kq = 0; kq < 64; kq++) {
        const uint4 y4 = *(const uint4*)&Ys[nl * 256 + 4 * kq];
        const uint4 w4 = *(const uint4*)&Ws[c * 256 + 4 * kq];
        a0 = dot2(y4.x, w4.x, a0);
        a1 = dot2(y4.y, w4.y, a1);
        a0 = dot2(y4.z, w4.z, a0);
        a1 = dot2(y4.w, w4.w, a1);
      }
      out[(size_t)(nb * 64 + nl) * 6 + c] = a0 + a1 + bm3[c];
    }
  }
}

// ---------------------------------------------------------------------------
extern "C" void kernel_launch(void* const* d_in, const int* in_sizes, int n_in,
                              void* d_out, int out_size, void* d_ws,
                              size_t ws_size, hipStream_t stream) {
  (void)in_sizes; (void)n_in; (void)out_size;
  const float* cnn  = (const float*)d_in[0];
  const float* gaze = (const float*)d_in[1];
  const float* W_lh = (const float*)d_in[2];
  const float* b_lh = (const float*)d_in[3];
  const float* W_cn = (const float*)d_in[4];
  const float* b_cn = (const float*)d_in[5];
  const float* w_wt = (const float*)d_in[6];
  const float* Wih  = (const float*)d_in[7];
  const float* Whh  = (const float*)d_in[8];
  const float* bih  = (const float*)d_in[9];
  const float* bhh  = (const float*)d_in[10];
  const float* Wh1  = (const float*)d_in[11];
  const float* bh1  = (const float*)d_in[12];
  const float* Wh2  = (const float*)d_in[13];
  const float* bh2  = (const float*)d_in[14];
  const float* Wc1  = (const float*)d_in[15];
  const float* bc1  = (const float*)d_in[16];
  const float* Wc2  = (const float*)d_in[17];
  const float* bc2  = (const float*)d_in[18];
  const float* Wm1  = (const float*)d_in[19];
  const float* bm1  = (const float*)d_in[20];
  const float* Wm2  = (const float*)d_in[21];
  const float* bm2  = (const float*)d_in[22];
  const float* Wm3  = (const float*)d_in[23];
  const float* bm3  = (const float*)d_in[24];
  float* out = (float*)d_out;

  unsigned* W = (unsigned*)d_ws;
  float* Wf = (float*)d_ws;
  // workspace offsets in dwords
  const size_t O_xg  = 0;                    // [31][64][256][4] f32
  const size_t O_wl  = 2031616;              // [1024][32]  u32
  const size_t O_wst = O_wl + 32768;         // [56][256][4] u32
  const size_t O_wvp = O_wst + 57344;        // [40][256][4] u32
  const size_t O_HH  = O_wvp + 40960;        // [33][64][256] f32
  const size_t O_c0  = O_HH + 540672;        // [64][256]   f32
  const size_t O_Hl  = O_c0 + 16384;         // [32][64][128] f32
  const size_t O_z   = O_Hl + 262144;        // [32][64][36] f32
  const size_t O_fc  = O_z + 73728;          // [2048][512] f32
  const size_t O_y1  = O_fc + 1048576;       // [2048][256] u32
  const size_t O_y2  = O_y1 + 524288;        // [2048][256] u32
  const size_t O_wcn = O_y2 + 524288;        // [128][128]  u32
  const size_t O_wlh = O_wcn + 16384;        // [128][128]  u32
  const size_t O_wm1 = O_wlh + 16384;        // [512][256]  u32
  const size_t O_wm2 = O_wm1 + 131072;
  const size_t O_wm3 = O_wm2 + 131072;       // [6][256]    u32
  const size_t O_vp  = O_wm3 + 1536;         // [32][2304][64] u32 (18.9MB)
  const size_t needed = (O_vp + 4718592) * 4ull;

  const bool big = ws_size >= needed;
  const int nvp = big ? 576 : 0;

  float* xg  = Wf + O_xg;
  float* HH  = Wf + O_HH;
  float* c0f = Wf + O_c0;
  float* Hlf = Wf + O_Hl;
  float* zf  = Wf + O_z;
  float* fcf = Wf + O_fc;
  unsigned* Vp = W + O_vp;

  // --- upfront (LSTM/Vp dependencies) ---
  k_pack_lstm<<<512, 256, 0, stream>>>(Whh, W + O_wl, W + O_wst, W + O_wvp);
  k_packh2<<<64, 256, 0, stream>>>(W_cn, W + O_wcn, 16384);
  k_xg<<<7936, 256, 0, stream>>>(gaze, Wih, bih, bhh, xg);
  k_init<<<64, 256, 0, stream>>>(gaze, Wh1, bh1, Wh2, bh2, Wc1, bc1, Wc2, bc2,
                                 HH, c0f);
  // --- fused: LSTM chains + (Vp GEMM + MLP packs) on idle CUs ---
  k_fused<<<64 + nvp + 17, 256, 0, stream>>>(
      xg, W + O_wst, W + O_wvp, W + O_wl, c0f, HH, cnn, W + O_wcn, b_cn, Vp,
      nvp, Wm1, W + O_wm1, Wm2, W + O_wm2, Wm3, W + O_wm3, W_lh, W + O_wlh);
  // --- batched attention ---
  k_hl<<<32, 256, 0, stream>>>(HH, W + O_wlh, b_lh, Hlf);
  if (big)
    k_zfin<<<576, 256, 0, stream>>>(Vp, Hlf, w_wt, zf);
  else
    k_att_z<<<576, 256, 0, stream>>>(cnn, W + O_wcn, b_cn, Hlf, w_wt, zf);
  k_att_sf<<<2048, 256, 0, stream>>>(cnn, zf, HH, fcf);
  // --- batched MLP ---
  k_mlp<0><<<128, 256, 0, stream>>>((const void*)fcf, W + O_wm1, bm1, W + O_y1);
  k_mlp<1><<<128, 256, 0, stream>>>((const void*)(W + O_y1), W + O_wm2, bm2, W + O_y2);
  k_mlp3<<<32, 256, 0, stream>>>(W + O_y2, W + O_wm3, bm3, out);
}

// Round 11
// 1071.613 us; speedup vs baseline: 16.4965x; 1.8324x over previous
//
#include <hip/hip_runtime.h>
#include <math.h>

// ---------------------------------------------------------------------------
// SpatialAttentionModel on MI355X.
// R11: LSTM = R6's proven compiler-streamed design (1024 thr, VGPR=64,
// 32 pairs LDS stride-36 + 96 pairs streamed from L2), with the stream
// repacked to 24 uint4 quads -> global_load_dwordx4 (1KB/wave/inst, 4x fewer
// stream instructions; R6 was issue-limited at VALUBusy 15%).
// No pins, no rings: R4-R10 proved the allocator converts >100 persistent
// dwords/thread into scratch traffic regardless of pinning strategy.
// Keeps R10's overlap: Vp GEMM (576 blks) + MLP/W_lh packs (17 blks) fused
// into the LSTM launch, running on the 192 idle CUs (refcheck'd in R10).
// ---------------------------------------------------------------------------

typedef _Float16 h2_t __attribute__((ext_vector_type(2)));

#if __has_builtin(__builtin_amdgcn_fdot2)
#define HAVE_FDOT2 1
#else
#define HAVE_FDOT2 0
#endif

__device__ __forceinline__ float dot2(unsigned w, unsigned h, float acc) {
#if HAVE_FDOT2
  return __builtin_amdgcn_fdot2(__builtin_bit_cast(h2_t, w),
                                __builtin_bit_cast(h2_t, h), acc, false);
#else
  h2_t a = __builtin_bit_cast(h2_t, w);
  h2_t b = __builtin_bit_cast(h2_t, h);
  return acc + (float)a[0] * (float)b[0] + (float)a[1] * (float)b[1];
#endif
}

__device__ __forceinline__ unsigned pack2(float a, float b) {
  h2_t p;
  p[0] = (_Float16)a;
  p[1] = (_Float16)b;
  return __builtin_bit_cast(unsigned, p);
}

__device__ __forceinline__ float sigmoid_f(float x) {
  return __builtin_amdgcn_rcpf(1.f + __expf(-x));
}
__device__ __forceinline__ float tanh_f(float x) {
  return 1.f - 2.f * __builtin_amdgcn_rcpf(1.f + __expf(2.f * x));
}

// ---------------------------------------------------------------------------
// Pack Whh:
//  wlds_pack[row*32+p], p<32: pairs 0..31 (static LDS tier)
//  wst  u32[24*1024*4] viewed as uint4[24][1024]: quad (m,row) = pairs
//       32+4m..35+4m of gate row `row` -> one dwordx4 per thread per quad.
__global__ void k_pack_lstm(const float* __restrict__ Whh,
                            unsigned* __restrict__ wlds_pack,
                            unsigned* __restrict__ wst) {
  const int idx = blockIdx.x * 256 + threadIdx.x;  // < 131072
  if (idx < 32768) {
    const int row = idx >> 5, pair = idx & 31;
    wlds_pack[idx] =
        pack2(Whh[row * 256 + 2 * pair], Whh[row * 256 + 2 * pair + 1]);
  } else {
    const int rel = idx - 32768;  // < 98304
    const int m = rel >> 12, row = (rel >> 2) & 1023, d = rel & 3;
    const int pair = 32 + 4 * m + d;
    wst[rel] = pack2(Whh[row * 256 + 2 * pair], Whh[row * 256 + 2 * pair + 1]);
  }
}

// Generic f32 -> packed-f16-pair converter.
__global__ void k_packh2(const float* __restrict__ src,
                         unsigned* __restrict__ dst, int n) {
  const int i = blockIdx.x * 256 + threadIdx.x;
  if (i < n) dst[i] = pack2(src[2 * i], src[2 * i + 1]);
}

// xg[t][b][j] = gaze[b,t,:]·Wih[j,:] + bih[j] + bhh[j]  (gate-major, R6).
__global__ void k_xg(const float* __restrict__ gaze,
                     const float* __restrict__ Wih,
                     const float* __restrict__ bih,
                     const float* __restrict__ bhh,
                     float* __restrict__ xg) {
  const int idx = blockIdx.x * 256 + threadIdx.x;
  if (idx >= 31 * 64 * 1024) return;
  const int j = idx & 1023;
  const int b = (idx >> 10) & 63;
  const int t = idx >> 16;
  const float* gz = gaze + (b * 32 + t) * 3;
  xg[idx] = gz[0] * Wih[j * 3 + 0] + gz[1] * Wih[j * 3 + 1] +
            gz[2] * Wih[j * 3 + 2] + bih[j] + bhh[j];
}

// h0/c0 init.
__global__ void k_init(const float* __restrict__ gaze,
                       const float* __restrict__ Wh1, const float* __restrict__ bh1,
                       const float* __restrict__ Wh2, const float* __restrict__ bh2,
                       const float* __restrict__ Wc1, const float* __restrict__ bc1,
                       const float* __restrict__ Wc2, const float* __restrict__ bc2,
                       float* __restrict__ HH, float* __restrict__ c0) {
  const int b = blockIdx.x;
  const int tid = threadIdx.x;  // 256
  __shared__ float mg[3];
  __shared__ float t1h[256], t1c[256];
  if (tid < 3) {
    float s = 0.f;
    for (int t = 0; t < 32; t++) s += gaze[(b * 32 + t) * 3 + tid];
    mg[tid] = s * (1.f / 32.f);
  }
  __syncthreads();
  {
    float a = mg[0] * Wh1[tid * 3 + 0] + mg[1] * Wh1[tid * 3 + 1] +
              mg[2] * Wh1[tid * 3 + 2] + bh1[tid];
    t1h[tid] = tanhf(a);
    float c = mg[0] * Wc1[tid * 3 + 0] + mg[1] * Wc1[tid * 3 + 1] +
              mg[2] * Wc1[tid * 3 + 2] + bc1[tid];
    t1c[tid] = tanhf(c);
  }
  __syncthreads();
  float s1 = bh2[tid], s2 = bc2[tid];
  for (int k = 0; k < 256; k++) {
    s1 += t1h[k] * Wh2[tid * 256 + k];
    s2 += t1c[k] * Wc2[tid * 256 + k];
  }
  HH[b * 256 + tid] = tanhf(tanhf(s1));
  c0[b * 256 + tid] = tanhf(tanhf(s2));
}

// ---------------------------------------------------------------------------
// Fused kernel (1024 threads/block):
//  blocks [0,64)          : LSTM chains (R6 structure + x4 stream)
//  blocks [64,64+nvp)     : Vp GEMM tiles
//  blocks [64+nvp, +17)   : MLP/W_lh weight packs
__global__ __launch_bounds__(1024) void k_fused(
    const float* __restrict__ xg, const unsigned* __restrict__ wst,
    const unsigned* __restrict__ wlds_pack, const float* __restrict__ c0,
    float* __restrict__ HH, const float* __restrict__ cnn,
    const unsigned* __restrict__ wcn_h2, const float* __restrict__ bcn,
    unsigned* __restrict__ Vp, int nvp, const float* __restrict__ Wm1,
    unsigned* __restrict__ wm1d, const float* __restrict__ Wm2,
    unsigned* __restrict__ wm2d, const float* __restrict__ Wm3,
    unsigned* __restrict__ wm3d, const float* __restrict__ Wlh,
    unsigned* __restrict__ wlhd) {
  const int bid = blockIdx.x;
  const int tid = threadIdx.x;
  __shared__ __align__(16) unsigned smem[38016];  // 152064 B (R6's footprint)

  if (bid < 64) {
    // ================= LSTM path (R6 + x4 stream) =================
    const int b = bid;
    unsigned* wlds = smem;                    // [1024*36]
    float* actl = (float*)(smem + 36864);     // [1024]
    unsigned* h2l = smem + 36864 + 1024;      // [128]

    for (int i = tid; i < 1024 * 32; i += 1024) {
      const int row = i >> 5, p = i & 31;
      wlds[row * 36 + p] = wlds_pack[i];
    }

    float cst = (tid < 256) ? c0[b * 256 + tid] : 0.f;
    if (tid < 256) ((_Float16*)h2l)[tid] = (_Float16)HH[b * 256 + tid];
    __syncthreads();

    const unsigned* wA = &wlds[tid * 36];
    const uint4* wstp = (const uint4*)wst + tid;
    const bool is_g = (tid >= 512) & (tid < 768);  // wave-uniform
    float hval = 0.f;

    for (int frame = 0; frame < 32; frame++) {
      const int L = frame ? frame : 1;
      for (int t = 0; t < L; t++) {
        const float xgv = xg[(t * 64 + b) * 1024 + tid];
        float ga0 = 0.f, ga1 = 0.f;
        // ---- LDS tier: pairs 0..31 ----
#pragma unroll
        for (int q = 0; q < 8; q++) {
          const uint4 h4 = *(const uint4*)&h2l[4 * q];
          const uint4 a4 = *(const uint4*)&wA[4 * q];
          if ((q & 1) == 0) {
            ga0 = dot2(a4.x, h4.x, ga0);
            ga0 = dot2(a4.y, h4.y, ga0);
            ga0 = dot2(a4.z, h4.z, ga0);
            ga0 = dot2(a4.w, h4.w, ga0);
          } else {
            ga1 = dot2(a4.x, h4.x, ga1);
            ga1 = dot2(a4.y, h4.y, ga1);
            ga1 = dot2(a4.z, h4.z, ga1);
            ga1 = dot2(a4.w, h4.w, ga1);
          }
        }
        // ---- streamed tier: pairs 32..127 as 24 dwordx4 loads ----
#pragma unroll
        for (int m = 0; m < 24; m++) {
          const uint4 wq = wstp[m << 10];
          const uint4 h4 = *(const uint4*)&h2l[32 + 4 * m];
          if ((m & 1) == 0) {
            ga0 = dot2(wq.x, h4.x, ga0);
            ga0 = dot2(wq.y, h4.y, ga0);
            ga0 = dot2(wq.z, h4.z, ga0);
            ga0 = dot2(wq.w, h4.w, ga0);
          } else {
            ga1 = dot2(wq.x, h4.x, ga1);
            ga1 = dot2(wq.y, h4.y, ga1);
            ga1 = dot2(wq.z, h4.z, ga1);
            ga1 = dot2(wq.w, h4.w, ga1);
          }
        }
        const float g = ga0 + ga1 + xgv;
        const float act = is_g ? tanh_f(g) : sigmoid_f(g);
        actl[tid] = act;
        __syncthreads();  // B1: h2l reads done; acts visible
        if (tid < 256) {
          const float i_ = actl[tid];
          const float f_ = actl[256 + tid];
          const float g_ = actl[512 + tid];
          const float o_ = actl[768 + tid];
          cst = f_ * cst + i_ * g_;
          hval = o_ * tanh_f(cst);
          ((_Float16*)h2l)[tid] = (_Float16)hval;
        }
        __syncthreads();  // B2: h2l ready for next step
      }
      if (tid < 256) HH[((frame + 1) * 64 + b) * 256 + tid] = hval;
    }
  } else if (bid < 64 + nvp) {
    // ================= Vp GEMM path (1024 threads) =================
    const int vb = bid - 64;  // < 576
    const int i = vb / 18, rt = vb - 18 * i;
    const int r0 = rt * 128;
    unsigned* As = smem;                   // 128*132
    unsigned* Bs = smem + 16896;           // 128*132
    float* bcs = (float*)(smem + 33792);   // 128

    for (int idx = tid; idx < 128 * 128; idx += 1024) {
      const int r = idx >> 7, kp = idx & 127;
      const int R = r0 + r;
      const int b = R / 36, g = R - b * 36;
      const float* src = cnn + (((size_t)b * 32 + i) * 36 + g) * 256 + 2 * kp;
      As[r * 132 + kp] = pack2(src[0], src[1]);
    }
    for (int idx = tid; idx < 128 * 128; idx += 1024) {
      const int o = idx >> 7, kp = idx & 127;
      Bs[o * 132 + kp] = wcn_h2[o * 128 + kp];
    }
    if (tid < 128) bcs[tid] = bcn[tid];
    __syncthreads();

    const int ry = tid >> 4, px = tid & 15;  // ry<64
    float acc[2][8];
#pragma unroll
    for (int k = 0; k < 2; k++)
#pragma unroll
      for (int m = 0; m < 8; m++)
        acc[k][m] = bcs[32 * (m >> 1) + 2 * px + (m & 1)];
    for (int kb = 0; kb < 32; kb++) {
      uint4 a4[2], b4[8];
#pragma unroll
      for (int k = 0; k < 2; k++)
        a4[k] = *(const uint4*)&As[(64 * k + ry) * 132 + 4 * kb];
#pragma unroll
      for (int m = 0; m < 8; m++)
        b4[m] = *(const uint4*)&Bs[(32 * (m >> 1) + 2 * px + (m & 1)) * 132 + 4 * kb];
#pragma unroll
      for (int k = 0; k < 2; k++)
#pragma unroll
        for (int m = 0; m < 8; m++) {
          acc[k][m] = dot2(a4[k].x, b4[m].x, acc[k][m]);
          acc[k][m] = dot2(a4[k].y, b4[m].y, acc[k][m]);
          acc[k][m] = dot2(a4[k].z, b4[m].z, acc[k][m]);
          acc[k][m] = dot2(a4[k].w, b4[m].w, acc[k][m]);
        }
    }
#pragma unroll
    for (int k = 0; k < 2; k++) {
      const int R = r0 + 64 * k + ry;
#pragma unroll
      for (int jj = 0; jj < 4; jj++)
        Vp[((size_t)i * 2304 + R) * 64 + 16 * jj + px] =
            pack2(acc[k][2 * jj], acc[k][2 * jj + 1]);
    }
  } else {
    // ================= pack path (17 blocks) =================
    const int pb = bid - 64 - nvp;
    if (pb < 8) {
      const int base = pb * 16384;
      for (int j = tid; j < 16384; j += 1024)
        wm1d[base + j] = pack2(Wm1[2 * (base + j)], Wm1[2 * (base + j) + 1]);
    } else if (pb < 16) {
      const int base = (pb - 8) * 16384;
      for (int j = tid; j < 16384; j += 1024)
        wm2d[base + j] = pack2(Wm2[2 * (base + j)], Wm2[2 * (base + j) + 1]);
    } else {
      for (int j = tid; j < 1536; j += 1024)
        wm3d[j] = pack2(Wm3[2 * j], Wm3[2 * j + 1]);
      for (int j = tid; j < 16384; j += 1024)
        wlhd[j] = pack2(Wlh[2 * j], Wlh[2 * j + 1]);
    }
  }
}

// z finish: z[b,g] = sum_p w[p]*tanh(Hl[i,b,p] + Vp[i,R,p]).
__global__ void k_zfin(const unsigned* __restrict__ Vp,
                       const float* __restrict__ Hl,
                       const float* __restrict__ wwt,
                       float* __restrict__ zbuf) {
  const int bid = blockIdx.x;  // 576
  const int i = bid / 18, rt = bid - 18 * i;
  const int r0 = rt * 128;
  const int tid = threadIdx.x;  // 256
  __shared__ float Hls[5 * 128];
  __shared__ float wws[128];
  __shared__ float zpart[128 * 16];
  const int bmin = r0 / 36;
  for (int idx = tid; idx < 5 * 128; idx += 256) {
    const int bb = bmin + (idx >> 7);
    if (bb < 64) Hls[idx] = Hl[(i * 64 + bb) * 128 + (idx & 127)];
  }
  if (tid < 128) wws[tid] = wwt[tid];
  __syncthreads();
  const int ry = tid >> 4, px = tid & 15;
#pragma unroll
  for (int k = 0; k < 8; k++) {
    const int r = 16 * k + ry;
    const int R = r0 + r;
    const int b = R / 36;
    const unsigned* vr = Vp + ((size_t)i * 2304 + R) * 64;
    const float* Hr = &Hls[(b - bmin) * 128];
    float z = 0.f;
#pragma unroll
    for (int jj = 0; jj < 4; jj++) {
      const int pp = 16 * jj + px;
      const h2_t pr = __builtin_bit_cast(h2_t, vr[pp]);
      z += wws[2 * pp] * tanh_f(Hr[2 * pp] + (float)pr[0]);
      z += wws[2 * pp + 1] * tanh_f(Hr[2 * pp + 1] + (float)pr[1]);
    }
    zpart[r * 16 + px] = z;
  }
  __syncthreads();
  if (tid < 128) {
    float z = 0.f;
#pragma unroll
    for (int x = 0; x < 16; x++) z += zpart[tid * 16 + x];
    const int R = r0 + tid;
    const int b = R / 36, g = R - b * 36;
    zbuf[(i * 64 + b) * 36 + g] = z;
  }
}

// Hl[i][b][p] = HH[i][b]·W_lh[p] + b_lh[p].
__global__ void k_hl(const float* __restrict__ HH,
                     const unsigned* __restrict__ wlh_h2,
                     const float* __restrict__ blh, float* __restrict__ Hl) {
  const int i = blockIdx.x;
  const int tid = threadIdx.x;  // 256
  __shared__ __align__(16) unsigned Ah[64 * 132];
  __shared__ __align__(16) unsigned Bh[128 * 132];
  for (int idx = tid; idx < 64 * 128; idx += 256) {
    const int r = idx >> 7, kp = idx & 127;
    const float* s = HH + ((size_t)(i * 64 + r)) * 256 + 2 * kp;
    Ah[r * 132 + kp] = pack2(s[0], s[1]);
  }
  for (int idx = tid; idx < 128 * 128; idx += 256) {
    const int o = idx >> 7, kp = idx & 127;
    Bh[o * 132 + kp] = wlh_h2[o * 128 + kp];
  }
  __syncthreads();
  const int ry = tid >> 4, px = tid & 15;
  float acc[4][8];
#pragma unroll
  for (int k = 0; k < 4; k++)
#pragma unroll
    for (int j = 0; j < 8; j++) acc[k][j] = 0.f;
  for (int kb = 0; kb < 32; kb++) {
    uint4 a4[4], b4[8];
#pragma unroll
    for (int k = 0; k < 4; k++) a4[k] = *(const uint4*)&Ah[(16 * k + ry) * 132 + 4 * kb];
#pragma unroll
    for (int j = 0; j < 8; j++) b4[j] = *(const uint4*)&Bh[(16 * j + px) * 132 + 4 * kb];
#pragma unroll
    for (int k = 0; k < 4; k++)
#pragma unroll
      for (int j = 0; j < 8; j++) {
        acc[k][j] = dot2(a4[k].x, b4[j].x, acc[k][j]);
        acc[k][j] = dot2(a4[k].y, b4[j].y, acc[k][j]);
        acc[k][j] = dot2(a4[k].z, b4[j].z, acc[k][j]);
        acc[k][j] = dot2(a4[k].w, b4[j].w, acc[k][j]);
      }
  }
#pragma unroll
  for (int k = 0; k < 4; k++)
#pragma unroll
    for (int j = 0; j < 8; j++)
      Hl[(i * 64 + 16 * k + ry) * 128 + 16 * j + px] = acc[k][j] + blh[16 * j + px];
}

// Fallback (small ws): fused Vp GEMM + z.
__global__ void k_att_z(const float* __restrict__ cnn,
                        const unsigned* __restrict__ wcn_h2,
                        const float* __restrict__ bcn,
                        const float* __restrict__ Hl,
                        const float* __restrict__ wwt,
                        float* __restrict__ zbuf) {
  const int bid = blockIdx.x;  // 576
  const int i = bid / 18, rt = bid - 18 * i;
  const int tid = threadIdx.x;  // 256
  const int r0 = rt * 128;
  __shared__ __align__(16) unsigned As[128 * 132];
  __shared__ __align__(16) unsigned Bs[128 * 132];
  __shared__ float zpart[128 * 16];
  __shared__ float Hls[5 * 128];
  __shared__ float wws[128];
  __shared__ float bcs[128];

  for (int idx = tid; idx < 128 * 128; idx += 256) {
    const int r = idx >> 7, kp = idx & 127;
    const int R = r0 + r;
    const int b = R / 36, g = R - b * 36;
    const float* src = cnn + (((size_t)b * 32 + i) * 36 + g) * 256 + 2 * kp;
    As[r * 132 + kp] = pack2(src[0], src[1]);
  }
  for (int idx = tid; idx < 128 * 128; idx += 256) {
    const int o = idx >> 7, kp = idx & 127;
    Bs[o * 132 + kp] = wcn_h2[o * 128 + kp];
  }
  const int bmin = r0 / 36;
  for (int idx = tid; idx < 5 * 128; idx += 256) {
    const int bb = bmin + (idx >> 7);
    if (bb < 64) Hls[idx] = Hl[(i * 64 + bb) * 128 + (idx & 127)];
  }
  if (tid < 128) {
    wws[tid] = wwt[tid];
    bcs[tid] = bcn[tid];
  }
  __syncthreads();

  const int ry = tid >> 4, px = tid & 15;
  float acc[8][8];
#pragma unroll
  for (int k = 0; k < 8; k++)
#pragma unroll
    for (int j = 0; j < 8; j++) acc[k][j] = bcs[16 * j + px];
  for (int kb = 0; kb < 32; kb++) {
    uint4 a4[8], b4[8];
#pragma unroll
    for (int k = 0; k < 8; k++) a4[k] = *(const uint4*)&As[(16 * k + ry) * 132 + 4 * kb];
#pragma unroll
    for (int j = 0; j < 8; j++) b4[j] = *(const uint4*)&Bs[(16 * j + px) * 132 + 4 * kb];
#pragma unroll
    for (int k = 0; k < 8; k++)
#pragma unroll
      for (int j = 0; j < 8; j++) {
        acc[k][j] = dot2(a4[k].x, b4[j].x, acc[k][j]);
        acc[k][j] = dot2(a4[k].y, b4[j].y, acc[k][j]);
        acc[k][j] = dot2(a4[k].z, b4[j].z, acc[k][j]);
        acc[k][j] = dot2(a4[k].w, b4[j].w, acc[k][j]);
      }
  }
#pragma unroll
  for (int k = 0; k < 8; k++) {
    const int r = 16 * k + ry;
    const int R = r0 + r;
    const int b = R / 36;
    const float* HlRow = &Hls[(b - bmin) * 128];
    float zp = 0.f;
#pragma unroll
    for (int j = 0; j < 8; j++) {
      const int po = 16 * j + px;
      zp += wws[po] * tanh_f(HlRow[po] + acc[k][j]);
    }
    zpart[r * 16 + px] = zp;
  }
  __syncthreads();
  if (tid < 128) {
    float z = 0.f;
#pragma unroll
    for (int x = 0; x < 16; x++) z += zpart[tid * 16 + x];
    const int R = r0 + tid;
    const int b = R / 36, g = R - b * 36;
    zbuf[(i * 64 + b) * 36 + g] = z;
  }
}

// Scrambled softmax + weighted V sum; builds fc = [spatial_feat | h_next].
__global__ void k_att_sf(const float* __restrict__ cnn,
                         const float* __restrict__ zbuf,
                         const float* __restrict__ HH,
                         float* __restrict__ fc) {
  const int bid = blockIdx.x;  // 2048
  const int i = bid >> 6, b = bid & 63;
  const int tid = threadIdx.x;  // 256
  __shared__ float zl[36];
  __shared__ float el[40];
  __shared__ float red[1];
  if (tid < 36) {
    const int idx = b * 36 + tid;
    zl[tid] = zbuf[(i * 64 + (idx & 63)) * 36 + (idx >> 6)];
  }
  __syncthreads();
  if (tid == 0) {
    float m = zl[0];
    for (int g = 1; g < 36; g++) m = fmaxf(m, zl[g]);
    float s = 0.f;
    for (int g = 0; g < 36; g++) {
      const float e = __expf(zl[g] - m);
      el[g] = e;
      s += e;
    }
    red[0] = 1.f / s;
  }
  __syncthreads();
  const float inv = red[0];
  float accv = 0.f;
  const float* Vb = cnn + (((size_t)b * 32 + i) * 36) * 256 + tid;
#pragma unroll 4
  for (int g = 0; g < 36; g++) accv += el[g] * Vb[g * 256];
  fc[(size_t)bid * 512 + tid] = accv * inv;
  fc[(size_t)bid * 512 + 256 + tid] = HH[((i + 1) * 64 + b) * 256 + tid];
}

// MLP layers 1/2.
template <int SRCMODE>
__global__ void k_mlp(const void* __restrict__ src,
                      const unsigned* __restrict__ wh2,
                      const float* __restrict__ bias,
                      unsigned* __restrict__ dst) {
  const int bid = blockIdx.x;  // 128
  const int nb = bid >> 2, ob = bid & 3;
  const int n0 = nb * 64, o0 = ob * 128;
  const int tid = threadIdx.x;
  __shared__ __align__(16) unsigned As[64 * 132];
  __shared__ __align__(16) unsigned Bs[128 * 132];
  const int ry = tid >> 4, px = tid & 15;
  float acc[4][8];
#pragma unroll
  for (int k = 0; k < 4; k++)
#pragma unroll
    for (int m = 0; m < 8; m++)
      acc[k][m] = bias[o0 + 32 * (m >> 1) + 2 * px + (m & 1)];
  for (int kc = 0; kc < 2; kc++) {
    __syncthreads();
    for (int idx = tid; idx < 64 * 128; idx += 256) {
      const int r = idx >> 7, kp = idx & 127;
      if (SRCMODE == 0) {
        const float* s = (const float*)src + ((size_t)(n0 + r)) * 512 + kc * 256 + 2 * kp;
        As[r * 132 + kp] = pack2(s[0], s[1]);
      } else {
        As[r * 132 + kp] = ((const unsigned*)src)[((size_t)(n0 + r)) * 256 + kc * 128 + kp];
      }
    }
    for (int idx = tid; idx < 128 * 128; idx += 256) {
      const int o = idx >> 7, kp = idx & 127;
      Bs[o * 132 + kp] = wh2[((size_t)(o0 + o)) * 256 + kc * 128 + kp];
    }
    __syncthreads();
    for (int kb = 0; kb < 32; kb++) {
      uint4 a4[4], b4[8];
#pragma unroll
      for (int k = 0; k < 4; k++)
        a4[k] = *(const uint4*)&As[(16 * k + ry) * 132 + 4 * kb];
#pragma unroll
      for (int m = 0; m < 8; m++)
        b4[m] = *(const uint4*)&Bs[(32 * (m >> 1) + 2 * px + (m & 1)) * 132 + 4 * kb];
#pragma unroll
      for (int k = 0; k < 4; k++)
#pragma unroll
        for (int m = 0; m < 8; m++) {
          acc[k][m] = dot2(a4[k].x, b4[m].x, acc[k][m]);
          acc[k][m] = dot2(a4[k].y, b4[m].y, acc[k][m]);
          acc[k][m] = dot2(a4[k].z, b4[m].z, acc[k][m]);
          acc[k][m] = dot2(a4[k].w, b4[m].w, acc[k][m]);
        }
    }
  }
#pragma unroll
  for (int k = 0; k < 4; k++) {
    const int n = n0 + 16 * k + ry;
#pragma unroll
    for (int j = 0; j < 4; j++)
      dst[(size_t)n * 256 + (o0 >> 1) + 16 * j + px] =
          pack2(acc[k][2 * j], acc[k][2 * j + 1]);
  }
}

// Final layer: (2048,512) -> 6 classes.
__global__ void k_mlp3(const unsigned* __restrict__ y2h2,
                       const unsigned* __restrict__ wm3h2,
                       const float* __restrict__ bm3,
                       float* __restrict__ out) {
  const int nb = blockIdx.x;  // 32
  const int tid = threadIdx.x;
  __shared__ __align__(16) unsigned Ys[64 * 256];
  __shared__ __align__(16) unsigned Ws[6 * 256];
  for (int idx = tid; idx < 64 * 256; idx += 256)
    Ys[idx] = y2h2[(size_t)nb * 64 * 256 + idx];
  for (int idx = tid; idx < 6 * 256; idx += 256) Ws[idx] = wm3h2[idx];
  __syncthreads();
  for (int u = 0; u < 2; u++) {
    const int idx = tid + u * 256;
    if (idx < 384) {
      const int nl = idx / 6, c = idx - 6 * nl;
      float a0 = 0.f, a1 = 0.f;
#pragma unroll
      for (int kq = 0; kq < 64; kq++) {
        const uint4 y4 = *(const uint4*)&Ys[nl * 256 + 4 * kq];
        const uint4 w4 = *(const uint4*)&Ws[c * 256 + 4 * kq];
        a0 = dot2(y4.x, w4.x, a0);
        a1 = dot2(y4.y, w4.y, a1);
        a0 = dot2(y4.z, w4.z, a0);
        a1 = dot2(y4.w, w4.w, a1);
      }
      out[(size_t)(nb * 64 + nl) * 6 + c] = a0 + a1 + bm3[c];
    }
  }
}

// ---------------------------------------------------------------------------
extern "C" void kernel_launch(void* const* d_in, const int* in_sizes, int n_in,
                              void* d_out, int out_size, void* d_ws,
                              size_t ws_size, hipStream_t stream) {
  (void)in_sizes; (void)n_in; (void)out_size;
  const float* cnn  = (const float*)d_in[0];
  const float* gaze = (const float*)d_in[1];
  const float* W_lh = (const float*)d_in[2];
  const float* b_lh = (const float*)d_in[3];
  const float* W_cn = (const float*)d_in[4];
  const float* b_cn = (const float*)d_in[5];
  const float* w_wt = (const float*)d_in[6];
  const float* Wih  = (const float*)d_in[7];
  const float* Whh  = (const float*)d_in[8];
  const float* bih  = (const float*)d_in[9];
  const float* bhh  = (const float*)d_in[10];
  const float* Wh1  = (const float*)d_in[11];
  const float* bh1  = (const float*)d_in[12];
  const float* Wh2  = (const float*)d_in[13];
  const float* bh2  = (const float*)d_in[14];
  const float* Wc1  = (const float*)d_in[15];
  const float* bc1  = (const float*)d_in[16];
  const float* Wc2  = (const float*)d_in[17];
  const float* bc2  = (const float*)d_in[18];
  const float* Wm1  = (const float*)d_in[19];
  const float* bm1  = (const float*)d_in[20];
  const float* Wm2  = (const float*)d_in[21];
  const float* bm2  = (const float*)d_in[22];
  const float* Wm3  = (const float*)d_in[23];
  const float* bm3  = (const float*)d_in[24];
  float* out = (float*)d_out;

  unsigned* W = (unsigned*)d_ws;
  float* Wf = (float*)d_ws;
  // workspace offsets in dwords
  const size_t O_xg  = 0;                    // [31][64][1024] f32
  const size_t O_wl  = 2031616;              // [1024][32]  u32
  const size_t O_wst = O_wl + 32768;         // [24][1024] uint4 = 98304 u32
  const size_t O_HH  = O_wst + 98304;        // [33][64][256] f32
  const size_t O_c0  = O_HH + 540672;        // [64][256]   f32
  const size_t O_Hl  = O_c0 + 16384;         // [32][64][128] f32
  const size_t O_z   = O_Hl + 262144;        // [32][64][36] f32
  const size_t O_fc  = O_z + 73728;          // [2048][512] f32
  const size_t O_y1  = O_fc + 1048576;       // [2048][256] u32
  const size_t O_y2  = O_y1 + 524288;        // [2048][256] u32
  const size_t O_wcn = O_y2 + 524288;        // [128][128]  u32
  const size_t O_wlh = O_wcn + 16384;        // [128][128]  u32
  const size_t O_wm1 = O_wlh + 16384;        // [512][256]  u32
  const size_t O_wm2 = O_wm1 + 131072;
  const size_t O_wm3 = O_wm2 + 131072;       // [6][256]    u32
  const size_t O_vp  = O_wm3 + 1536;         // [32][2304][64] u32 (18.9MB)
  const size_t needed = (O_vp + 4718592) * 4ull;

  const bool big = ws_size >= needed;
  const int nvp = big ? 576 : 0;

  float* xg  = Wf + O_xg;
  float* HH  = Wf + O_HH;
  float* c0f = Wf + O_c0;
  float* Hlf = Wf + O_Hl;
  float* zf  = Wf + O_z;
  float* fcf = Wf + O_fc;
  unsigned* Vp = W + O_vp;

  // --- upfront (LSTM/Vp dependencies) ---
  k_pack_lstm<<<512, 256, 0, stream>>>(Whh, W + O_wl, W + O_wst);
  k_packh2<<<64, 256, 0, stream>>>(W_cn, W + O_wcn, 16384);
  k_xg<<<7936, 256, 0, stream>>>(gaze, Wih, bih, bhh, xg);
  k_init<<<64, 256, 0, stream>>>(gaze, Wh1, bh1, Wh2, bh2, Wc1, bc1, Wc2, bc2,
                                 HH, c0f);
  // --- fused: LSTM chains + (Vp GEMM + MLP packs) on idle CUs ---
  k_fused<<<64 + nvp + 17, 1024, 0, stream>>>(
      xg, W + O_wst, W + O_wl, c0f, HH, cnn, W + O_wcn, b_cn, Vp, nvp, Wm1,
      W + O_wm1, Wm2, W + O_wm2, Wm3, W + O_wm3, W_lh, W + O_wlh);
  // --- batched attention ---
  k_hl<<<32, 256, 0, stream>>>(HH, W + O_wlh, b_lh, Hlf);
  if (big)
    k_zfin<<<576, 256, 0, stream>>>(Vp, Hlf, w_wt, zf);
  else
    k_att_z<<<576, 256, 0, stream>>>(cnn, W + O_wcn, b_cn, Hlf, w_wt, zf);
  k_att_sf<<<2048, 256, 0, stream>>>(cnn, zf, HH, fcf);
  // --- batched MLP ---
  k_mlp<0><<<128, 256, 0, stream>>>((const void*)fcf, W + O_wm1, bm1, W + O_y1);
  k_mlp<1><<<128, 256, 0, stream>>>((const void*)(W + O_y1), W + O_wm2, bm2, W + O_y2);
  k_mlp3<<<32, 256, 0, stream>>>(W + O_y2, W + O_wm3, bm3, out);
}